// Round 18
// baseline (183.235 us; speedup 1.0000x reference)
//
#include <hip/hip_runtime.h>
#include <hip/hip_bf16.h>
#include <math.h>

// Sparse MHA encoder: B=4, S=1024, D=1024, H=16, dk=64.
// Numerics: the 0.09 threshold is a step function on first-pass softmax.
// Score path (Q/K projections + QK^T) is split-bf16 (hi+lo, ~2^-18 rel err)
// -> E[mask flips] ~1e-4. Post-mask paths (PV, ctx, O-proj) direct bf16.
// Pass B recomputes scores BIT-IDENTICALLY to pass A (same helper, same LDS).
// Uniform-row skip: row all-masked <=> rowmax < tau = log(0.09*Z).
// R18: attn pass A -> T3/T4 counted-vmcnt pipeline: 3-buffer LDS ring,
// stage TWO chunks ahead via gld_lds, per-chunk `s_waitcnt vmcnt(4)` +
// raw s_barrier (never drain to 0 in the loop). R17's one-ahead +
// __syncthreads drained the just-issued loads every chunk (m97 stall).
// Pass B (rare, ~2% of blocks) keeps full __syncthreads semantics.

constexpr int D_MODEL = 1024;
constexpr int N_HEADS = 16;
constexpr int D_HEAD  = 64;
constexpr int SEQ     = 1024;
constexpr int BATCH   = 4;
constexpr float SPARSE_THRESH = 0.09f;

typedef short  bf16x8 __attribute__((ext_vector_type(8)));
typedef float  f32x4  __attribute__((ext_vector_type(4)));

__device__ __forceinline__ unsigned short f2bf_rne(float x) {
    unsigned u = __float_as_uint(x);
    u += 0x7FFFu + ((u >> 16) & 1u);          // round-to-nearest-even
    return (unsigned short)(u >> 16);
}
__device__ __forceinline__ float bf2f(unsigned short b) {
    return __uint_as_float(((unsigned)b) << 16);
}

// packed RNE pair-convert: low16 = bf16(a), high16 = bf16(b)  (v_cvt_pk_bf16_f32)
__device__ __forceinline__ unsigned cvt2(float a, float b) {
    __hip_bfloat162 p = __float22bfloat162_rn(make_float2(a, b));
    unsigned u; __builtin_memcpy(&u, &p, 4); return u;
}
// split 4 floats -> 2 packed hi words + 2 packed lo words
__device__ __forceinline__ void split4(float x0, float x1, float x2, float x3,
                                       unsigned* hw, unsigned* lw) {
    const unsigned uh0 = cvt2(x0, x1);
    hw[0] = uh0;
    lw[0] = cvt2(x0 - __uint_as_float(uh0 << 16),
                 x1 - __uint_as_float(uh0 & 0xFFFF0000u));
    const unsigned uh1 = cvt2(x2, x3);
    hw[1] = uh1;
    lw[1] = cvt2(x2 - __uint_as_float(uh1 << 16),
                 x3 - __uint_as_float(uh1 & 0xFFFF0000u));
}

union BF8 { unsigned u[4]; bf16x8 v; };

// 8 packed words (hi<<16|lo) -> hi bf16x8 + lo bf16x8
__device__ __forceinline__ void unpack_pair(const unsigned* u, bf16x8& hi, bf16x8& lo) {
    BF8 h, l;
    #pragma unroll
    for (int p = 0; p < 4; ++p) {
        h.u[p] = (u[2 * p] >> 16)      | (u[2 * p + 1] & 0xFFFF0000u);
        l.u[p] = (u[2 * p] & 0xFFFFu)  | (u[2 * p + 1] << 16);
    }
    hi = h.v; lo = l.v;
}

// 16B global -> LDS direct copy (wave-uniform LDS base + lane*16)
__device__ __forceinline__ void gld_lds16(const void* g, void* l) {
    __builtin_amdgcn_global_load_lds(
        (const __attribute__((address_space(1))) void*)g,
        (__attribute__((address_space(3))) void*)l, 16, 0, 0);
}

// ============ weight pre-split: Wq/Wk/Wv -> hi/lo bf16 planes ============
__global__ __launch_bounds__(256)
void conv_w(const float* __restrict__ Wq, const float* __restrict__ Wk,
            const float* __restrict__ Wv,
            unsigned short* __restrict__ Wqh, unsigned short* __restrict__ Wql,
            unsigned short* __restrict__ Wkh, unsigned short* __restrict__ Wkl,
            unsigned short* __restrict__ Wvh, unsigned short* __restrict__ Wvl)
{
    const int NW8 = (D_MODEL * D_MODEL) / 8;      // 131072
    int i = blockIdx.x * 256 + threadIdx.x;
    const float* s; unsigned short *dh, *dl;
    if (i < NW8)            { s = Wq; dh = Wqh; dl = Wql; }
    else if (i < 2 * NW8)   { i -= NW8; s = Wk; dh = Wkh; dl = Wkl; }
    else                    { i -= 2 * NW8; s = Wv; dh = Wvh; dl = Wvl; }
    const float4 x0 = ((const float4*)(s + (size_t)i * 8))[0];
    const float4 x1 = ((const float4*)(s + (size_t)i * 8))[1];
    unsigned hw[4], lw[4];
    split4(x0.x, x0.y, x0.z, x0.w, &hw[0], &lw[0]);
    split4(x1.x, x1.y, x1.z, x1.w, &hw[2], &lw[2]);
    *(uint4*)&dh[(size_t)i * 8] = *(const uint4*)hw;
    *(uint4*)&dl[(size_t)i * 8] = *(const uint4*)lw;
}

// ============ fused Q/K/V projection (256 thr, 64x64/wave) ============
// z selects {Q,K,V}. A (input) split in-loop via cvt_pk; W pre-split planes.
// z==0: Q packed u32 (hi<<16|lo) head-split [B,H,S,dk], scaled 1/8.
// z==1: K -> TWO bf16 planes (hi/lo), head-split, d PRE-SWIZZLED by
//       d ^= (s&7)<<3 (matches attn's LDS read XOR; gld_lds copies linear).
// z==2: V bf16 plane TRANSPOSED [B,H,dk,S] via LDS bounce, 256B-run stores.
// Grid (32,8,3): x=bm -> id%8 = bm%8 (A-row XCD locality).
__global__ __launch_bounds__(256, 3)
void proj_qkv(const float* __restrict__ q, const float* __restrict__ k,
              const float* __restrict__ v,
              const unsigned short* __restrict__ Wqh, const unsigned short* __restrict__ Wql,
              const unsigned short* __restrict__ Wkh, const unsigned short* __restrict__ Wkl,
              const unsigned short* __restrict__ Wvh, const unsigned short* __restrict__ Wvl,
              const float* __restrict__ bq, const float* __restrict__ bk,
              const float* __restrict__ bv,
              unsigned* __restrict__ qp,
              unsigned short* __restrict__ khh, unsigned short* __restrict__ khl,
              unsigned short* __restrict__ vt)
{
    __shared__ unsigned short SM[4][128][40];   // A_h, A_l, B_h, B_l
    unsigned short (*A_h)[40] = SM[0];
    unsigned short (*A_l)[40] = SM[1];
    unsigned short (*B_h)[40] = SM[2];
    unsigned short (*B_l)[40] = SM[3];

    const int z = blockIdx.z;
    const float* X    = (z == 0) ? q   : (z == 1) ? k   : v;
    const unsigned short* Wh = (z == 0) ? Wqh : (z == 1) ? Wkh : Wvh;
    const unsigned short* Wl = (z == 0) ? Wql : (z == 1) ? Wkl : Wvl;
    const float* bias = (z == 0) ? bq  : (z == 1) ? bk  : bv;

    const int K = D_MODEL;
    const int tid = threadIdx.x, lane = tid & 63;
    const int l15 = lane & 15, l4 = lane >> 4;
    const int wv4 = tid >> 6;
    const int wr = (wv4 >> 1) * 64, wc = (wv4 & 1) * 64;
    const int bm = blockIdx.x * 128, bn = blockIdx.y * 128;   // x=bm (XCD locality)
    const int sr = tid >> 1, sh = (tid & 1) * 16;

    f32x4 acc[4][4];
    #pragma unroll
    for (int i = 0; i < 4; ++i)
        #pragma unroll
        for (int j = 0; j < 4; ++j) acc[i][j] = (f32x4){0.f, 0.f, 0.f, 0.f};

    const float* ga = X + (size_t)(bm + sr) * K + sh;
    const unsigned short* gbh = Wh + (size_t)(bn + sr) * K + sh;
    const unsigned short* gbl = Wl + (size_t)(bn + sr) * K + sh;

    float4 av[4];
    uint4 wbh0, wbh1, wbl0, wbl1;
    #pragma unroll
    for (int l = 0; l < 4; ++l) av[l] = *(const float4*)&ga[l * 4];
    wbh0 = *(const uint4*)&gbh[0]; wbh1 = *(const uint4*)&gbh[8];
    wbl0 = *(const uint4*)&gbl[0]; wbl1 = *(const uint4*)&gbl[8];

    #pragma unroll 1
    for (int k0 = 0; k0 < K; k0 += 32) {
        // split A (cvt_pk path: ~3 VALU/value; productive latency filler)
        unsigned ahw[8], alw[8];
        #pragma unroll
        for (int l = 0; l < 4; ++l)
            split4(av[l].x, av[l].y, av[l].z, av[l].w, &ahw[l * 2], &alw[l * 2]);

        __syncthreads();                 // prior frag reads done
        *(uint4*)&A_h[sr][sh]     = *(const uint4*)&ahw[0];
        *(uint4*)&A_h[sr][sh + 8] = *(const uint4*)&ahw[4];
        *(uint4*)&A_l[sr][sh]     = *(const uint4*)&alw[0];
        *(uint4*)&A_l[sr][sh + 8] = *(const uint4*)&alw[4];
        *(uint4*)&B_h[sr][sh]     = wbh0;
        *(uint4*)&B_h[sr][sh + 8] = wbh1;
        *(uint4*)&B_l[sr][sh]     = wbl0;
        *(uint4*)&B_l[sr][sh + 8] = wbl1;
        __syncthreads();                 // tiles ready

        if (k0 + 32 < K) {               // issue next-step loads under MFMA
            const int o = k0 + 32;
            #pragma unroll
            for (int l = 0; l < 4; ++l) av[l] = *(const float4*)&ga[o + l * 4];
            wbh0 = *(const uint4*)&gbh[o]; wbh1 = *(const uint4*)&gbh[o + 8];
            wbl0 = *(const uint4*)&gbl[o]; wbl1 = *(const uint4*)&gbl[o + 8];
        }

        bf16x8 ah[4], al4[4], bh4[4], bl4[4];
        #pragma unroll
        for (int i = 0; i < 4; ++i) {
            const int r = wr + i * 16 + l15;
            const int c = wc + i * 16 + l15;
            ah[i]  = *(const bf16x8*)&A_h[r][l4 * 8];
            al4[i] = *(const bf16x8*)&A_l[r][l4 * 8];
            bh4[i] = *(const bf16x8*)&B_h[c][l4 * 8];
            bl4[i] = *(const bf16x8*)&B_l[c][l4 * 8];
        }
        #pragma unroll
        for (int i = 0; i < 4; ++i)
            #pragma unroll
            for (int j = 0; j < 4; ++j) {
                acc[i][j] = __builtin_amdgcn_mfma_f32_16x16x32_bf16(ah[i],  bh4[j], acc[i][j], 0, 0, 0);
                acc[i][j] = __builtin_amdgcn_mfma_f32_16x16x32_bf16(ah[i],  bl4[j], acc[i][j], 0, 0, 0);
                acc[i][j] = __builtin_amdgcn_mfma_f32_16x16x32_bf16(al4[i], bh4[j], acc[i][j], 0, 0, 0);
            }
    }

    if (z == 2) {
        // V: transpose bounce -> vt[B,H,dk,S]; 256B-run coalesced stores
        unsigned short* T = &SM[0][0][0];            // [128][136]
        __syncthreads();
        #pragma unroll
        for (int i = 0; i < 4; ++i)
            #pragma unroll
            for (int j = 0; j < 4; ++j) {
                const int cl = wc + j * 16 + l15;
                const int sl = wr + i * 16 + l4 * 4;
                const float bi = bias[bn + cl];
                unsigned short h4[4];
                #pragma unroll
                for (int r = 0; r < 4; ++r)
                    h4[r] = f2bf_rne(acc[i][j][r] + bi);
                *(uint2*)&T[cl * 136 + sl] = *(const uint2*)&h4[0];
            }
        __syncthreads();
        const int c = tid >> 1, half = tid & 1;
        const int bb = bm >> 10;
        const int sb = (bm & (SEQ - 1)) + half * 64;
        unsigned short* dst = vt + (((size_t)bb << 20) + (size_t)(bn + c) * SEQ + sb);
        const unsigned short* srcT = &T[c * 136 + half * 64];
        #pragma unroll
        for (int u = 0; u < 8; ++u)
            *(uint4*)&dst[u * 8] = *(const uint4*)&srcT[u * 8];
        return;
    }

    if (z == 0) {
        // Q: packed u32, head-split, scaled by 1/8
        #pragma unroll
        for (int i = 0; i < 4; ++i)
            #pragma unroll
            for (int j = 0; j < 4; ++j) {
                const int rb = bm + wr + i * 16 + l4 * 4;
                const int c  = bn + wc + j * 16 + l15;
                const float bi = bias[c];
                const int h = c >> 6, d = c & (D_HEAD - 1);
                #pragma unroll
                for (int r = 0; r < 4; ++r) {
                    const float val = (acc[i][j][r] + bi) * 0.125f;
                    const unsigned short hu = f2bf_rne(val);
                    const unsigned short lu = f2bf_rne(val - bf2f(hu));
                    const int mrow = rb + r;
                    const int b = mrow >> 10, s = mrow & (SEQ - 1);
                    qp[((size_t)(b * N_HEADS + h) * SEQ + s) * D_HEAD + d] =
                        ((unsigned)hu << 16) | lu;
                }
            }
    } else {
        // K: two bf16 planes, d pre-swizzled (d ^ (s&7)<<3) for attn gld_lds
        #pragma unroll
        for (int i = 0; i < 4; ++i)
            #pragma unroll
            for (int j = 0; j < 4; ++j) {
                const int rb = bm + wr + i * 16 + l4 * 4;
                const int c  = bn + wc + j * 16 + l15;
                const float bi = bias[c];
                const int h = c >> 6, d = c & (D_HEAD - 1);
                #pragma unroll
                for (int r = 0; r < 4; ++r) {
                    const float val = acc[i][j][r] + bi;
                    const unsigned short hu = f2bf_rne(val);
                    const unsigned short lu = f2bf_rne(val - bf2f(hu));
                    const int mrow = rb + r;
                    const int b = mrow >> 10, s = mrow & (SEQ - 1);
                    const int dsw = d ^ ((s & 7) << 3);
                    const size_t off = ((size_t)(b * N_HEADS + h) * SEQ + s) * D_HEAD + dsw;
                    khh[off] = hu;
                    khl[off] = lu;
                }
            }
    }
}

// ============ O projection: bf16 ctx plane x hi(Wo), fp32 out ============
__global__ __launch_bounds__(256, 3)
void proj_o(const unsigned short* __restrict__ Act, const float* __restrict__ W,
            const float* __restrict__ bias, float* __restrict__ out)
{
    __shared__ unsigned short A_h[128][40];
    __shared__ unsigned short B_h[128][40];

    const int K = D_MODEL;
    const int tid = threadIdx.x, lane = tid & 63;
    const int l15 = lane & 15, l4 = lane >> 4;
    const int wv4 = tid >> 6;
    const int wr = (wv4 >> 1) * 64, wc = (wv4 & 1) * 64;
    const int bm = blockIdx.x * 128, bn = blockIdx.y * 128;
    const int sr = tid >> 1, sh = (tid & 1) * 16;

    f32x4 acc[4][4];
    #pragma unroll
    for (int i = 0; i < 4; ++i)
        #pragma unroll
        for (int j = 0; j < 4; ++j) acc[i][j] = (f32x4){0.f, 0.f, 0.f, 0.f};

    const unsigned short* ga = Act + (size_t)(bm + sr) * K + sh;
    const float* gb = W + (size_t)(bn + sr) * K + sh;

    uint4 av0 = *(const uint4*)&ga[0], av1 = *(const uint4*)&ga[8];
    float4 bv4[4];
    #pragma unroll
    for (int l = 0; l < 4; ++l) bv4[l] = *(const float4*)&gb[l * 4];

    #pragma unroll 1
    for (int k0 = 0; k0 < K; k0 += 32) {
        unsigned bhw[8];
        #pragma unroll
        for (int l = 0; l < 4; ++l) {
            bhw[l * 2]     = cvt2(bv4[l].x, bv4[l].y);
            bhw[l * 2 + 1] = cvt2(bv4[l].z, bv4[l].w);
        }

        __syncthreads();
        *(uint4*)&A_h[sr][sh]     = av0;
        *(uint4*)&A_h[sr][sh + 8] = av1;
        *(uint4*)&B_h[sr][sh]     = *(const uint4*)&bhw[0];
        *(uint4*)&B_h[sr][sh + 8] = *(const uint4*)&bhw[4];
        __syncthreads();

        if (k0 + 32 < K) {
            av0 = *(const uint4*)&ga[k0 + 32];
            av1 = *(const uint4*)&ga[k0 + 32 + 8];
            #pragma unroll
            for (int l = 0; l < 4; ++l)
                bv4[l] = *(const float4*)&gb[k0 + 32 + l * 4];
        }

        bf16x8 ah[4], bh4[4];
        #pragma unroll
        for (int i = 0; i < 4; ++i) {
            ah[i]  = *(const bf16x8*)&A_h[wr + i * 16 + l15][l4 * 8];
            bh4[i] = *(const bf16x8*)&B_h[wc + i * 16 + l15][l4 * 8];
        }
        #pragma unroll
        for (int i = 0; i < 4; ++i)
            #pragma unroll
            for (int j = 0; j < 4; ++j)
                acc[i][j] = __builtin_amdgcn_mfma_f32_16x16x32_bf16(ah[i], bh4[j], acc[i][j], 0, 0, 0);
    }

    #pragma unroll
    for (int i = 0; i < 4; ++i)
        #pragma unroll
        for (int j = 0; j < 4; ++j) {
            const int rb = bm + wr + i * 16 + l4 * 4;
            const int c  = bn + wc + j * 16 + l15;
            const float bi = bias[c];
            #pragma unroll
            for (int r = 0; r < 4; ++r)
                out[(size_t)(rb + r) * D_MODEL + c] = acc[i][j][r] + bi;
        }
}

// ============ MFMA attention (counted-vmcnt pipelined K staging) ============
// KH/KL rows are swizzled: element (k,d) lives at [k][d ^ ((k&7)<<3)].
__device__ __forceinline__ void score_from_lds(
    const unsigned short (* __restrict__ KH)[64], const unsigned short (* __restrict__ KL)[64],
    int l15, int dk0, int dk1,
    const bf16x8 (&qh)[2][2], const bf16x8 (&ql)[2][2], f32x4 acc[2][4])
{
    #pragma unroll
    for (int j = 0; j < 4; ++j) {
        const int row = l15 + 16 * j;                 // (row&7) == (l15&7)
        const bf16x8 kh0 = *(const bf16x8*)&KH[row][dk0];
        const bf16x8 kh1 = *(const bf16x8*)&KH[row][dk1];
        const bf16x8 kl0 = *(const bf16x8*)&KL[row][dk0];
        const bf16x8 kl1 = *(const bf16x8*)&KL[row][dk1];
        #pragma unroll
        for (int st = 0; st < 2; ++st) {
            f32x4 a = (f32x4){0.f, 0.f, 0.f, 0.f};
            a = __builtin_amdgcn_mfma_f32_16x16x32_bf16(qh[st][0], kh0, a, 0, 0, 0);
            a = __builtin_amdgcn_mfma_f32_16x16x32_bf16(qh[st][0], kl0, a, 0, 0, 0);
            a = __builtin_amdgcn_mfma_f32_16x16x32_bf16(ql[st][0], kh0, a, 0, 0, 0);
            a = __builtin_amdgcn_mfma_f32_16x16x32_bf16(qh[st][1], kh1, a, 0, 0, 0);
            a = __builtin_amdgcn_mfma_f32_16x16x32_bf16(qh[st][1], kl1, a, 0, 0, 0);
            a = __builtin_amdgcn_mfma_f32_16x16x32_bf16(ql[st][1], kh1, a, 0, 0, 0);
            acc[st][j] = a;
        }
    }
}

__global__ __launch_bounds__(256, 2)
void attn_mfma(const unsigned* __restrict__ qp,
               const unsigned short* __restrict__ khh, const unsigned short* __restrict__ khl,
               const unsigned short* __restrict__ vt, unsigned short* __restrict__ ctxh)
{
    __shared__ unsigned short KHL[3][2][64][64];   // 3-buffer ring, LINEAR dest
    __shared__ unsigned short Wl[4][32][64];       // per-wave W bf16 [q][k]
    __shared__ float Vm[64];
    __shared__ int AnyNU;
    float (*Pm)[4] = (float (*)[4])&Wl[0][0][0];   // aliased; disjoint lifetime

    const int tid  = threadIdx.x;
    const int lane = tid & 63;
    const int wv   = tid >> 6;
    const int l15  = lane & 15, l4 = lane >> 4;
    const int bh   = blockIdx.x;                   // XCD locality: id%8 = bh%8
    const int b    = bh >> 4, h = bh & 15;
    const int q0   = blockIdx.y * 128 + wv * 32;

    const int swz = (l15 & 7) << 3;
    const int dk0 = (l4 * 8) ^ swz;
    const int dk1 = (32 + l4 * 8) ^ swz;

    // ---- Q fragments (packed -> hi/lo) ----
    bf16x8 qh[2][2], ql[2][2];
    #pragma unroll
    for (int st = 0; st < 2; ++st) {
        const unsigned* qrow = qp + ((size_t)bh * SEQ + q0 + st * 16 + l15) * D_HEAD;
        #pragma unroll
        for (int ks = 0; ks < 2; ++ks) {
            unsigned u[8];
            *(uint4*)&u[0] = *(const uint4*)&qrow[ks * 32 + l4 * 8];
            *(uint4*)&u[4] = *(const uint4*)&qrow[ks * 32 + l4 * 8 + 4];
            unpack_pair(u, qh[st][ks], ql[st][ks]);
        }
    }

    const unsigned short* vtb = vt + (size_t)bh * D_HEAD * SEQ;

    // ---- vmean partials ----
    {
        const int d = tid >> 2, q4 = tid & 3;
        const unsigned short* vr = vtb + (size_t)d * SEQ + q4 * 256;
        float s0 = 0.f, s1 = 0.f, s2 = 0.f, s3 = 0.f;
        #pragma unroll 4
        for (int i = 0; i < 32; ++i) {
            bf16x8 v8 = *(const bf16x8*)&vr[i * 8];
            s0 += bf2f((unsigned short)v8[0]) + bf2f((unsigned short)v8[4]);
            s1 += bf2f((unsigned short)v8[1]) + bf2f((unsigned short)v8[5]);
            s2 += bf2f((unsigned short)v8[2]) + bf2f((unsigned short)v8[6]);
            s3 += bf2f((unsigned short)v8[3]) + bf2f((unsigned short)v8[7]);
        }
        Pm[d][q4] = (s0 + s1) + (s2 + s3);
        if (tid == 0) AnyNU = 0;
    }

    // staging: wave wv covers k-rows [wv*16, wv*16+16); lane -> row +(lane>>3),
    // d-halves (lane&7)*8. 4 gld_lds per wave per chunk (2 rows-groups x 2 planes).
    const size_t kbase = (size_t)bh * SEQ * D_HEAD;
    const int krow0 = wv * 16 + (lane >> 3);
    const int dgrp  = (lane & 7) * 8;

    #define STAGE_CHUNK(cidx, bufi)                                               \
        {   const int _c = (cidx);                                                \
            _Pragma("unroll")                                                     \
            for (int t = 0; t < 2; ++t) {                                         \
                const size_t src = kbase + ((size_t)_c * 64 + krow0 + t * 8) * D_HEAD + dgrp; \
                gld_lds16(khh + src, &KHL[bufi][0][wv * 16 + t * 8][0]);          \
                gld_lds16(khl + src, &KHL[bufi][1][wv * 16 + t * 8][0]);          \
            } }

    // prologue: stage chunks 0,1 -> bufs 0,1 (full drain via __syncthreads:
    // also publishes Pm writes)
    STAGE_CHUNK(0, 0);
    STAGE_CHUNK(1, 1);
    __syncthreads();

    if (tid < 64)
        Vm[tid] = (Pm[tid][0] + Pm[tid][1] + Pm[tid][2] + Pm[tid][3]) * (1.f / 1024.f);

    float mloc[2][4], zloc[2][4];
    #pragma unroll
    for (int st = 0; st < 2; ++st)
        #pragma unroll
        for (int r = 0; r < 4; ++r) { mloc[st][r] = -1e30f; zloc[st][r] = 0.f; }

    // ========== pass A: counted-vmcnt 3-buffer pipeline ==========
    // invariant at loop top: buf c%3 and (c+1)%3 resident / c+1 possibly in
    // flight but landed by the previous iteration's vmcnt(4)+barrier.
    #pragma unroll 1
    for (int c = 0; c < 16; ++c) {
        const int rb = c % 3;
        const int ib = (c + 2) % 3;
        STAGE_CHUNK((c + 2) & 15, ib);             // issue 2-ahead (4 loads/wave)

        f32x4 acc[2][4];
        score_from_lds(KHL[rb][0], KHL[rb][1], l15, dk0, dk1, qh, ql, acc);

        #pragma unroll
        for (int st = 0; st < 2; ++st)
            #pragma unroll
            for (int r = 0; r < 4; ++r) {
                const float a0 = acc[st][0][r], a1 = acc[st][1][r];
                const float a2 = acc[st][2][r], a3 = acc[st][3][r];
                mloc[st][r] = fmaxf(mloc[st][r], fmaxf(fmaxf(a0, a1), fmaxf(a2, a3)));
                zloc[st][r] += (__expf(a0) + __expf(a1)) + (__expf(a2) + __expf(a3));
            }

        // T4: wait until only the 2-ahead chunk's 4 loads remain in flight;
        // chunk c+1 is then LDS-resident for every wave after the barrier.
        asm volatile("s_waitcnt vmcnt(4)" ::: "memory");
        __builtin_amdgcn_sched_barrier(0);
        __builtin_amdgcn_s_barrier();
        __builtin_amdgcn_sched_barrier(0);
    }

    // ---- merge; tau test; uniform detect ----
    float taue[2][4];
    bool  unif[2][4];
    int mynu = 0;
    #pragma unroll
    for (int st = 0; st < 2; ++st)
        #pragma unroll
        for (int r = 0; r < 4; ++r) {
            float mm = mloc[st][r], zz = zloc[st][r];
            #pragma unroll
            for (int o = 1; o <= 8; o <<= 1) {
                mm = fmaxf(mm, __shfl_xor(mm, o, 16));
                zz += __shfl_xor(zz, o, 16);
            }
            const float tau = __logf(SPARSE_THRESH * zz);
            const bool uni = (mm < tau);
            unif[st][r] = uni;
            taue[st][r] = uni ? 3.0e38f : tau;
            mynu |= uni ? 0 : 1;
        }
    if (__any(mynu)) { if (lane == 0) atomicOr(&AnyNU, 1); }
    __syncthreads();                               // drains stragglers too
    const bool runB = (AnyNU != 0);

    float z2[2][4];
    f32x4 pv[2][4];
    #pragma unroll
    for (int st = 0; st < 2; ++st)
        #pragma unroll
        for (int r = 0; r < 4; ++r) { z2[st][r] = 0.f; pv[st][r] = (f32x4){0.f, 0.f, 0.f, 0.f}; }

    // ========== pass B: rare; plain __syncthreads cadence, 1-ahead ==========
    if (runB) {
        STAGE_CHUNK(0, 0);
        __syncthreads();

        #pragma unroll 1
        for (int c = 0; c < 16; ++c) {
            const int rb = c % 3;
            const int ib = (c + 1) % 3;
            STAGE_CHUNK((c + 1) & 15, ib);

            f32x4 acc[2][4];
            score_from_lds(KHL[rb][0], KHL[rb][1], l15, dk0, dk1, qh, ql, acc);  // bit-identical

            int any = 0;
            #pragma unroll
            for (int st = 0; st < 2; ++st)
                #pragma unroll
                for (int r = 0; r < 4; ++r) {
                    const float rmax = fmaxf(fmaxf(acc[st][0][r], acc[st][1][r]),
                                             fmaxf(acc[st][2][r], acc[st][3][r]));
                    any |= (rmax >= taue[st][r]) ? 1 : 0;
                }

            if (__any(any)) {
                #pragma unroll
                for (int st = 0; st < 2; ++st)
                    #pragma unroll
                    for (int j = 0; j < 4; ++j)
                        #pragma unroll
                        for (int r = 0; r < 4; ++r) {
                            const float a = acc[st][j][r];
                            const float w = (a >= taue[st][r]) ? __expf(a) : 0.f;
                            const unsigned short wb = f2bf_rne(w);
                            z2[st][r] += bf2f(wb);
                            Wl[wv][st * 16 + l4 * 4 + r][l15 + 16 * j] = wb;
                        }
                asm volatile("s_waitcnt lgkmcnt(0)" ::: "memory");
                __builtin_amdgcn_sched_barrier(0);

                bf16x8 wa[2][2];
                #pragma unroll
                for (int st = 0; st < 2; ++st)
                    #pragma unroll
                    for (int ks = 0; ks < 2; ++ks)
                        wa[st][ks] = *(const bf16x8*)&Wl[wv][st * 16 + l15][ks * 32 + l4 * 8];

                #pragma unroll
                for (int ds = 0; ds < 4; ++ds) {
                    const bf16x8 v0 = *(const bf16x8*)
                        &vtb[(size_t)(ds * 16 + l15) * SEQ + c * 64 + l4 * 8];
                    const bf16x8 v1 = *(const bf16x8*)
                        &vtb[(size_t)(ds * 16 + l15) * SEQ + c * 64 + 32 + l4 * 8];
                    #pragma unroll
                    for (int st = 0; st < 2; ++st) {
                        pv[st][ds] = __builtin_amdgcn_mfma_f32_16x16x32_bf16(wa[st][0], v0, pv[st][ds], 0, 0, 0);
                        pv[st][ds] = __builtin_amdgcn_mfma_f32_16x16x32_bf16(wa[st][1], v1, pv[st][ds], 0, 0, 0);
                    }
                }
            }

            __syncthreads();
        }

        #pragma unroll
        for (int st = 0; st < 2; ++st)
            #pragma unroll
            for (int r = 0; r < 4; ++r) {
                #pragma unroll
                for (int o = 1; o <= 8; o <<= 1) z2[st][r] += __shfl_xor(z2[st][r], o, 16);
            }
    }

    // ---- epilogue: select vmean vs pv/z2; bounce via KHL (stride 64) ----
    float* Tw = (float*)&KHL[0][0][0][0] + wv * 2048;   // per-wave [32][64] f32
    __syncthreads();                                    // all KHL reads/writes done
    #pragma unroll
    for (int st = 0; st < 2; ++st)
        #pragma unroll
        for (int r = 0; r < 4; ++r) {
            const float inv = unif[st][r] ? 0.f : (1.f / z2[st][r]);
            const int row = st * 16 + l4 * 4 + r;
            #pragma unroll
            for (int ds = 0; ds < 4; ++ds) {
                const int d = ds * 16 + l15;
                Tw[row * 64 + d] = unif[st][r] ? Vm[d] : pv[st][ds][r] * inv;
            }
        }
    asm volatile("s_waitcnt lgkmcnt(0)" ::: "memory");
    __builtin_amdgcn_sched_barrier(0);

    const int rr = lane >> 1, seg = lane & 1;
    const size_t gbase = ((size_t)b * SEQ + q0 + rr) * D_MODEL + h * D_HEAD + seg * 32;
    #pragma unroll
    for (int u2 = 0; u2 < 8; ++u2) {
        const float4 t = *(const float4*)&Tw[rr * 64 + seg * 32 + u2 * 4];
        unsigned short h4[4] = {f2bf_rne(t.x), f2bf_rne(t.y), f2bf_rne(t.z), f2bf_rne(t.w)};
        *(uint2*)&ctxh[gbase + u2 * 4] = *(const uint2*)h4;
    }
    #undef STAGE_CHUNK
}

extern "C" void kernel_launch(void* const* d_in, const int* in_sizes, int n_in,
                              void* d_out, int out_size, void* d_ws, size_t ws_size,
                              hipStream_t stream)
{
    const float* q  = (const float*)d_in[0];
    const float* k  = (const float*)d_in[1];
    const float* v  = (const float*)d_in[2];
    const float* Wq = (const float*)d_in[3];
    const float* bq = (const float*)d_in[4];
    const float* Wk = (const float*)d_in[5];
    const float* bk = (const float*)d_in[6];
    const float* Wv = (const float*)d_in[7];
    const float* bv = (const float*)d_in[8];
    const float* Wo = (const float*)d_in[9];
    const float* bo = (const float*)d_in[10];
    float* out = (float*)d_out;

    // workspace (60 MiB): qp 16 + khh 8 + khl 8 + vt 8 + ctxh 8 + W planes 12
    const size_t MB = 1 << 20;
    char* w = (char*)d_ws;
    unsigned* qp = (unsigned*)(w);
    unsigned short* khh  = (unsigned short*)(w + 16 * MB);
    unsigned short* khl  = (unsigned short*)(w + 24 * MB);
    unsigned short* vt   = (unsigned short*)(w + 32 * MB);
    unsigned short* ctxh = (unsigned short*)(w + 40 * MB);
    unsigned short* Wqh = (unsigned short*)(w + 48 * MB);
    unsigned short* Wql = (unsigned short*)(w + 50 * MB);
    unsigned short* Wkh = (unsigned short*)(w + 52 * MB);
    unsigned short* Wkl = (unsigned short*)(w + 54 * MB);
    unsigned short* Wvh = (unsigned short*)(w + 56 * MB);
    unsigned short* Wvl = (unsigned short*)(w + 58 * MB);

    const int NW8 = (D_MODEL * D_MODEL) / 8;      // 131072

    // pre-split the 3 weight matrices
    conv_w<<<(3 * NW8) / 256, 256, 0, stream>>>(Wq, Wk, Wv, Wqh, Wql, Wkh, Wkl, Wvh, Wvl);

    // fused Q/K/V: grid (32,8,3), x=bm -> id%8 = bm%8 (A-row XCD locality)
    proj_qkv<<<dim3(32, 8, 3), 256, 0, stream>>>(q, k, v,
                                                 Wqh, Wql, Wkh, Wkl, Wvh, Wvl,
                                                 bq, bk, bv, qp, khh, khl, vt);

    // bh on x: all 8 q-blocks of a (b,h) share an XCD (id%8 = bh%8)
    attn_mfma<<<dim3(BATCH * N_HEADS, SEQ / 128), 256, 0, stream>>>(qp, khh, khl, vt, ctxh);

    proj_o<<<dim3(32, 8), 256, 0, stream>>>(ctxh, Wo, bo, out);
}

// Round 19
// 178.217 us; speedup vs baseline: 1.0282x; 1.0282x over previous
//
#include <hip/hip_runtime.h>
#include <hip/hip_bf16.h>
#include <math.h>

// Sparse MHA encoder: B=4, S=1024, D=1024, H=16, dk=64.
// Numerics: the 0.09 threshold is a step function on first-pass softmax.
// Score path (Q/K projections + QK^T) is split-bf16 (hi+lo, ~2^-18 rel err)
// -> E[mask flips] ~1e-4. Post-mask paths (PV, ctx, O-proj) direct bf16.
// Pass B recomputes scores BIT-IDENTICALLY to pass A (same helper, same LDS).
// Uniform-row skip: row all-masked <=> rowmax < tau = log(0.09*Z).
// R19: REVERT to the best-measured configuration (R16, 178.6us). Post-mortem
// of R16-R18: three structural nulls on attn staging (occupancy bump, gld_lds
// +swizzle, counted-vmcnt ring) => attn's residual stall is the lockstep
// chunk dependency chain, not staging latency. proj_qkv is at its 2-barrier
// structure ceiling (~35% MfmaUtil). Locking in the best state.

constexpr int D_MODEL = 1024;
constexpr int N_HEADS = 16;
constexpr int D_HEAD  = 64;
constexpr int SEQ     = 1024;
constexpr int BATCH   = 4;
constexpr float SPARSE_THRESH = 0.09f;

typedef short  bf16x8 __attribute__((ext_vector_type(8)));
typedef float  f32x4  __attribute__((ext_vector_type(4)));

__device__ __forceinline__ unsigned short f2bf_rne(float x) {
    unsigned u = __float_as_uint(x);
    u += 0x7FFFu + ((u >> 16) & 1u);          // round-to-nearest-even
    return (unsigned short)(u >> 16);
}
__device__ __forceinline__ float bf2f(unsigned short b) {
    return __uint_as_float(((unsigned)b) << 16);
}

// packed RNE pair-convert: low16 = bf16(a), high16 = bf16(b)  (v_cvt_pk_bf16_f32)
__device__ __forceinline__ unsigned cvt2(float a, float b) {
    __hip_bfloat162 p = __float22bfloat162_rn(make_float2(a, b));
    unsigned u; __builtin_memcpy(&u, &p, 4); return u;
}
// split 4 floats -> 2 packed hi words + 2 packed lo words
__device__ __forceinline__ void split4(float x0, float x1, float x2, float x3,
                                       unsigned* hw, unsigned* lw) {
    const unsigned uh0 = cvt2(x0, x1);
    hw[0] = uh0;
    lw[0] = cvt2(x0 - __uint_as_float(uh0 << 16),
                 x1 - __uint_as_float(uh0 & 0xFFFF0000u));
    const unsigned uh1 = cvt2(x2, x3);
    hw[1] = uh1;
    lw[1] = cvt2(x2 - __uint_as_float(uh1 << 16),
                 x3 - __uint_as_float(uh1 & 0xFFFF0000u));
}

union BF8 { unsigned u[4]; bf16x8 v; };

// 8 packed words (hi<<16|lo) -> hi bf16x8 + lo bf16x8
__device__ __forceinline__ void unpack_pair(const unsigned* u, bf16x8& hi, bf16x8& lo) {
    BF8 h, l;
    #pragma unroll
    for (int p = 0; p < 4; ++p) {
        h.u[p] = (u[2 * p] >> 16)      | (u[2 * p + 1] & 0xFFFF0000u);
        l.u[p] = (u[2 * p] & 0xFFFFu)  | (u[2 * p + 1] << 16);
    }
    hi = h.v; lo = l.v;
}

// ============ weight pre-split: Wq/Wk/Wv -> hi/lo bf16 planes ============
__global__ __launch_bounds__(256)
void conv_w(const float* __restrict__ Wq, const float* __restrict__ Wk,
            const float* __restrict__ Wv,
            unsigned short* __restrict__ Wqh, unsigned short* __restrict__ Wql,
            unsigned short* __restrict__ Wkh, unsigned short* __restrict__ Wkl,
            unsigned short* __restrict__ Wvh, unsigned short* __restrict__ Wvl)
{
    const int NW8 = (D_MODEL * D_MODEL) / 8;      // 131072
    int i = blockIdx.x * 256 + threadIdx.x;
    const float* s; unsigned short *dh, *dl;
    if (i < NW8)            { s = Wq; dh = Wqh; dl = Wql; }
    else if (i < 2 * NW8)   { i -= NW8; s = Wk; dh = Wkh; dl = Wkl; }
    else                    { i -= 2 * NW8; s = Wv; dh = Wvh; dl = Wvl; }
    const float4 x0 = ((const float4*)(s + (size_t)i * 8))[0];
    const float4 x1 = ((const float4*)(s + (size_t)i * 8))[1];
    unsigned hw[4], lw[4];
    split4(x0.x, x0.y, x0.z, x0.w, &hw[0], &lw[0]);
    split4(x1.x, x1.y, x1.z, x1.w, &hw[2], &lw[2]);
    *(uint4*)&dh[(size_t)i * 8] = *(const uint4*)hw;
    *(uint4*)&dl[(size_t)i * 8] = *(const uint4*)lw;
}

// ============ fused Q/K/V projection (256 thr, 64x64/wave) ============
// z selects {Q,K,V}. A (input) split in-loop via cvt_pk; W pre-split planes.
// z<2: packed u32 (hi<<16|lo) head-split [B,H,S,dk], scaled (Q: 1/8).
// z==2: bf16 plane TRANSPOSED [B,H,dk,S] via LDS bounce, 256B-run stores.
// Grid (32,8,3): x=bm -> id%8 = bm%8 (A-row XCD locality).
__global__ __launch_bounds__(256, 3)
void proj_qkv(const float* __restrict__ q, const float* __restrict__ k,
              const float* __restrict__ v,
              const unsigned short* __restrict__ Wqh, const unsigned short* __restrict__ Wql,
              const unsigned short* __restrict__ Wkh, const unsigned short* __restrict__ Wkl,
              const unsigned short* __restrict__ Wvh, const unsigned short* __restrict__ Wvl,
              const float* __restrict__ bq, const float* __restrict__ bk,
              const float* __restrict__ bv,
              unsigned* __restrict__ qp, unsigned* __restrict__ kp,
              unsigned short* __restrict__ vt)
{
    __shared__ unsigned short SM[4][128][40];   // A_h, A_l, B_h, B_l
    unsigned short (*A_h)[40] = SM[0];
    unsigned short (*A_l)[40] = SM[1];
    unsigned short (*B_h)[40] = SM[2];
    unsigned short (*B_l)[40] = SM[3];

    const int z = blockIdx.z;
    const float* X    = (z == 0) ? q   : (z == 1) ? k   : v;
    const unsigned short* Wh = (z == 0) ? Wqh : (z == 1) ? Wkh : Wvh;
    const unsigned short* Wl = (z == 0) ? Wql : (z == 1) ? Wkl : Wvl;
    const float* bias = (z == 0) ? bq  : (z == 1) ? bk  : bv;
    const float scale = (z == 0) ? 0.125f : 1.0f;

    const int K = D_MODEL;
    const int tid = threadIdx.x, lane = tid & 63;
    const int l15 = lane & 15, l4 = lane >> 4;
    const int wv4 = tid >> 6;
    const int wr = (wv4 >> 1) * 64, wc = (wv4 & 1) * 64;
    const int bm = blockIdx.x * 128, bn = blockIdx.y * 128;   // x=bm (XCD locality)
    const int sr = tid >> 1, sh = (tid & 1) * 16;

    f32x4 acc[4][4];
    #pragma unroll
    for (int i = 0; i < 4; ++i)
        #pragma unroll
        for (int j = 0; j < 4; ++j) acc[i][j] = (f32x4){0.f, 0.f, 0.f, 0.f};

    const float* ga = X + (size_t)(bm + sr) * K + sh;
    const unsigned short* gbh = Wh + (size_t)(bn + sr) * K + sh;
    const unsigned short* gbl = Wl + (size_t)(bn + sr) * K + sh;

    float4 av[4];
    uint4 wbh0, wbh1, wbl0, wbl1;
    #pragma unroll
    for (int l = 0; l < 4; ++l) av[l] = *(const float4*)&ga[l * 4];
    wbh0 = *(const uint4*)&gbh[0]; wbh1 = *(const uint4*)&gbh[8];
    wbl0 = *(const uint4*)&gbl[0]; wbl1 = *(const uint4*)&gbl[8];

    #pragma unroll 1
    for (int k0 = 0; k0 < K; k0 += 32) {
        // split A (cvt_pk path: ~3 VALU/value; productive latency filler)
        unsigned ahw[8], alw[8];
        #pragma unroll
        for (int l = 0; l < 4; ++l)
            split4(av[l].x, av[l].y, av[l].z, av[l].w, &ahw[l * 2], &alw[l * 2]);

        __syncthreads();                 // prior frag reads done
        *(uint4*)&A_h[sr][sh]     = *(const uint4*)&ahw[0];
        *(uint4*)&A_h[sr][sh + 8] = *(const uint4*)&ahw[4];
        *(uint4*)&A_l[sr][sh]     = *(const uint4*)&alw[0];
        *(uint4*)&A_l[sr][sh + 8] = *(const uint4*)&alw[4];
        *(uint4*)&B_h[sr][sh]     = wbh0;
        *(uint4*)&B_h[sr][sh + 8] = wbh1;
        *(uint4*)&B_l[sr][sh]     = wbl0;
        *(uint4*)&B_l[sr][sh + 8] = wbl1;
        __syncthreads();                 // tiles ready

        if (k0 + 32 < K) {               // issue next-step loads under MFMA
            const int o = k0 + 32;
            #pragma unroll
            for (int l = 0; l < 4; ++l) av[l] = *(const float4*)&ga[o + l * 4];
            wbh0 = *(const uint4*)&gbh[o]; wbh1 = *(const uint4*)&gbh[o + 8];
            wbl0 = *(const uint4*)&gbl[o]; wbl1 = *(const uint4*)&gbl[o + 8];
        }

        bf16x8 ah[4], al4[4], bh4[4], bl4[4];
        #pragma unroll
        for (int i = 0; i < 4; ++i) {
            const int r = wr + i * 16 + l15;
            const int c = wc + i * 16 + l15;
            ah[i]  = *(const bf16x8*)&A_h[r][l4 * 8];
            al4[i] = *(const bf16x8*)&A_l[r][l4 * 8];
            bh4[i] = *(const bf16x8*)&B_h[c][l4 * 8];
            bl4[i] = *(const bf16x8*)&B_l[c][l4 * 8];
        }
        #pragma unroll
        for (int i = 0; i < 4; ++i)
            #pragma unroll
            for (int j = 0; j < 4; ++j) {
                acc[i][j] = __builtin_amdgcn_mfma_f32_16x16x32_bf16(ah[i],  bh4[j], acc[i][j], 0, 0, 0);
                acc[i][j] = __builtin_amdgcn_mfma_f32_16x16x32_bf16(ah[i],  bl4[j], acc[i][j], 0, 0, 0);
                acc[i][j] = __builtin_amdgcn_mfma_f32_16x16x32_bf16(al4[i], bh4[j], acc[i][j], 0, 0, 0);
            }
    }

    if (z == 2) {
        // V: transpose bounce -> vt[B,H,dk,S]; 256B-run coalesced stores
        unsigned short* T = &SM[0][0][0];            // [128][136]
        __syncthreads();
        #pragma unroll
        for (int i = 0; i < 4; ++i)
            #pragma unroll
            for (int j = 0; j < 4; ++j) {
                const int cl = wc + j * 16 + l15;
                const int sl = wr + i * 16 + l4 * 4;
                const float bi = bias[bn + cl];
                unsigned short h4[4];
                #pragma unroll
                for (int r = 0; r < 4; ++r)
                    h4[r] = f2bf_rne(acc[i][j][r] + bi);
                *(uint2*)&T[cl * 136 + sl] = *(const uint2*)&h4[0];
            }
        __syncthreads();
        const int c = tid >> 1, half = tid & 1;
        const int bb = bm >> 10;
        const int sb = (bm & (SEQ - 1)) + half * 64;
        unsigned short* dst = vt + (((size_t)bb << 20) + (size_t)(bn + c) * SEQ + sb);
        const unsigned short* srcT = &T[c * 136 + half * 64];
        #pragma unroll
        for (int u = 0; u < 8; ++u)
            *(uint4*)&dst[u * 8] = *(const uint4*)&srcT[u * 8];
        return;
    }

    // Q/K: packed u32, head-split
    unsigned* Cp = (z == 0) ? qp : kp;
    #pragma unroll
    for (int i = 0; i < 4; ++i)
        #pragma unroll
        for (int j = 0; j < 4; ++j) {
            const int rb = bm + wr + i * 16 + l4 * 4;
            const int c  = bn + wc + j * 16 + l15;
            const float bi = bias[c];
            const int h = c >> 6, d = c & (D_HEAD - 1);
            #pragma unroll
            for (int r = 0; r < 4; ++r) {
                const float val = (acc[i][j][r] + bi) * scale;
                const unsigned short hu = f2bf_rne(val);
                const unsigned short lu = f2bf_rne(val - bf2f(hu));
                const int mrow = rb + r;
                const int b = mrow >> 10, s = mrow & (SEQ - 1);
                Cp[((size_t)(b * N_HEADS + h) * SEQ + s) * D_HEAD + d] =
                    ((unsigned)hu << 16) | lu;
            }
        }
}

// ============ O projection: bf16 ctx plane x hi(Wo), fp32 out ============
__global__ __launch_bounds__(256, 3)
void proj_o(const unsigned short* __restrict__ Act, const float* __restrict__ W,
            const float* __restrict__ bias, float* __restrict__ out)
{
    __shared__ unsigned short A_h[128][40];
    __shared__ unsigned short B_h[128][40];

    const int K = D_MODEL;
    const int tid = threadIdx.x, lane = tid & 63;
    const int l15 = lane & 15, l4 = lane >> 4;
    const int wv4 = tid >> 6;
    const int wr = (wv4 >> 1) * 64, wc = (wv4 & 1) * 64;
    const int bm = blockIdx.x * 128, bn = blockIdx.y * 128;
    const int sr = tid >> 1, sh = (tid & 1) * 16;

    f32x4 acc[4][4];
    #pragma unroll
    for (int i = 0; i < 4; ++i)
        #pragma unroll
        for (int j = 0; j < 4; ++j) acc[i][j] = (f32x4){0.f, 0.f, 0.f, 0.f};

    const unsigned short* ga = Act + (size_t)(bm + sr) * K + sh;
    const float* gb = W + (size_t)(bn + sr) * K + sh;

    uint4 av0 = *(const uint4*)&ga[0], av1 = *(const uint4*)&ga[8];
    float4 bv4[4];
    #pragma unroll
    for (int l = 0; l < 4; ++l) bv4[l] = *(const float4*)&gb[l * 4];

    #pragma unroll 1
    for (int k0 = 0; k0 < K; k0 += 32) {
        unsigned bhw[8];
        #pragma unroll
        for (int l = 0; l < 4; ++l) {
            bhw[l * 2]     = cvt2(bv4[l].x, bv4[l].y);
            bhw[l * 2 + 1] = cvt2(bv4[l].z, bv4[l].w);
        }

        __syncthreads();
        *(uint4*)&A_h[sr][sh]     = av0;
        *(uint4*)&A_h[sr][sh + 8] = av1;
        *(uint4*)&B_h[sr][sh]     = *(const uint4*)&bhw[0];
        *(uint4*)&B_h[sr][sh + 8] = *(const uint4*)&bhw[4];
        __syncthreads();

        if (k0 + 32 < K) {
            av0 = *(const uint4*)&ga[k0 + 32];
            av1 = *(const uint4*)&ga[k0 + 32 + 8];
            #pragma unroll
            for (int l = 0; l < 4; ++l)
                bv4[l] = *(const float4*)&gb[k0 + 32 + l * 4];
        }

        bf16x8 ah[4], bh4[4];
        #pragma unroll
        for (int i = 0; i < 4; ++i) {
            ah[i]  = *(const bf16x8*)&A_h[wr + i * 16 + l15][l4 * 8];
            bh4[i] = *(const bf16x8*)&B_h[wc + i * 16 + l15][l4 * 8];
        }
        #pragma unroll
        for (int i = 0; i < 4; ++i)
            #pragma unroll
            for (int j = 0; j < 4; ++j)
                acc[i][j] = __builtin_amdgcn_mfma_f32_16x16x32_bf16(ah[i], bh4[j], acc[i][j], 0, 0, 0);
    }

    #pragma unroll
    for (int i = 0; i < 4; ++i)
        #pragma unroll
        for (int j = 0; j < 4; ++j) {
            const int rb = bm + wr + i * 16 + l4 * 4;
            const int c  = bn + wc + j * 16 + l15;
            const float bi = bias[c];
            #pragma unroll
            for (int r = 0; r < 4; ++r)
                out[(size_t)(rb + r) * D_MODEL + c] = acc[i][j][r] + bi;
        }
}

// ============ MFMA attention (reg-staged K, Wl-diet, 3 blocks/CU) ============
__device__ __forceinline__ void score_from_lds(
    const unsigned short (* __restrict__ KH)[72], const unsigned short (* __restrict__ KL)[72],
    int l15, int l4, const bf16x8 (&qh)[2][2], const bf16x8 (&ql)[2][2], f32x4 acc[2][4])
{
    #pragma unroll
    for (int j = 0; j < 4; ++j) {
        const int row = l15 + 16 * j;
        const bf16x8 kh0 = *(const bf16x8*)&KH[row][l4 * 8];
        const bf16x8 kh1 = *(const bf16x8*)&KH[row][32 + l4 * 8];
        const bf16x8 kl0 = *(const bf16x8*)&KL[row][l4 * 8];
        const bf16x8 kl1 = *(const bf16x8*)&KL[row][32 + l4 * 8];
        #pragma unroll
        for (int st = 0; st < 2; ++st) {
            f32x4 a = (f32x4){0.f, 0.f, 0.f, 0.f};
            a = __builtin_amdgcn_mfma_f32_16x16x32_bf16(qh[st][0], kh0, a, 0, 0, 0);
            a = __builtin_amdgcn_mfma_f32_16x16x32_bf16(qh[st][0], kl0, a, 0, 0, 0);
            a = __builtin_amdgcn_mfma_f32_16x16x32_bf16(ql[st][0], kh0, a, 0, 0, 0);
            a = __builtin_amdgcn_mfma_f32_16x16x32_bf16(qh[st][1], kh1, a, 0, 0, 0);
            a = __builtin_amdgcn_mfma_f32_16x16x32_bf16(qh[st][1], kl1, a, 0, 0, 0);
            a = __builtin_amdgcn_mfma_f32_16x16x32_bf16(ql[st][1], kh1, a, 0, 0, 0);
            acc[st][j] = a;
        }
    }
}

__global__ __launch_bounds__(256, 3)
void attn_mfma(const unsigned* __restrict__ qp, const unsigned* __restrict__ kp,
               const unsigned short* __restrict__ vt, unsigned short* __restrict__ ctxh)
{
    __shared__ unsigned short KHL[2][2][64][72];
    __shared__ unsigned short Wl[4][32][64];       // stride 64: LDS diet
    __shared__ float Vm[64];
    __shared__ int AnyNU;
    // Pm aliased into Wl: Pm dead after Vm is computed (prologue barrier);
    // Wl first written in pass B. Disjoint lifetimes, barrier-separated.
    float (*Pm)[4] = (float (*)[4])&Wl[0][0][0];

    const int tid  = threadIdx.x;
    const int lane = tid & 63;
    const int wv   = tid >> 6;
    const int l15  = lane & 15, l4 = lane >> 4;
    const int bh   = blockIdx.x;                   // XCD locality: id%8 = bh%8
    const int b    = bh >> 4, h = bh & 15;
    const int q0   = blockIdx.y * 128 + wv * 32;

    bf16x8 qh[2][2], ql[2][2];
    #pragma unroll
    for (int st = 0; st < 2; ++st) {
        const unsigned* qrow = qp + ((size_t)bh * SEQ + q0 + st * 16 + l15) * D_HEAD;
        #pragma unroll
        for (int ks = 0; ks < 2; ++ks) {
            unsigned u[8];
            *(uint4*)&u[0] = *(const uint4*)&qrow[ks * 32 + l4 * 8];
            *(uint4*)&u[4] = *(const uint4*)&qrow[ks * 32 + l4 * 8 + 4];
            unpack_pair(u, qh[st][ks], ql[st][ks]);
        }
    }

    const unsigned short* vtb = vt + (size_t)bh * D_HEAD * SEQ;

    {
        const int d = tid >> 2, q4 = tid & 3;
        const unsigned short* vr = vtb + (size_t)d * SEQ + q4 * 256;
        float s0 = 0.f, s1 = 0.f, s2 = 0.f, s3 = 0.f;
        #pragma unroll 4
        for (int i = 0; i < 32; ++i) {
            bf16x8 v8 = *(const bf16x8*)&vr[i * 8];
            s0 += bf2f((unsigned short)v8[0]) + bf2f((unsigned short)v8[4]);
            s1 += bf2f((unsigned short)v8[1]) + bf2f((unsigned short)v8[5]);
            s2 += bf2f((unsigned short)v8[2]) + bf2f((unsigned short)v8[6]);
            s3 += bf2f((unsigned short)v8[3]) + bf2f((unsigned short)v8[7]);
        }
        Pm[d][q4] = (s0 + s1) + (s2 + s3);
        if (tid == 0) AnyNU = 0;
    }

    const int sr = tid >> 2;
    const int sd = (tid & 3) * 16;
    const unsigned* kpb = kp + (size_t)bh * SEQ * D_HEAD;

    {
        unsigned u[16];
        const unsigned* src = kpb + (size_t)sr * D_HEAD + sd;
        #pragma unroll
        for (int g = 0; g < 4; ++g) *(uint4*)&u[g * 4] = *(const uint4*)&src[g * 4];
        bf16x8 h0, l0, h1, l1;
        unpack_pair(&u[0], h0, l0);
        unpack_pair(&u[8], h1, l1);
        *(bf16x8*)&KHL[0][0][sr][sd]     = h0;
        *(bf16x8*)&KHL[0][0][sr][sd + 8] = h1;
        *(bf16x8*)&KHL[0][1][sr][sd]     = l0;
        *(bf16x8*)&KHL[0][1][sr][sd + 8] = l1;
    }
    __syncthreads();

    if (tid < 64)
        Vm[tid] = (Pm[tid][0] + Pm[tid][1] + Pm[tid][2] + Pm[tid][3]) * (1.f / 1024.f);

    float mloc[2][4], zloc[2][4];
    #pragma unroll
    for (int st = 0; st < 2; ++st)
        #pragma unroll
        for (int r = 0; r < 4; ++r) { mloc[st][r] = -1e30f; zloc[st][r] = 0.f; }

    int cur = 0;

    #pragma unroll 1
    for (int c = 0; c < 16; ++c) {
        unsigned u[16];
        const int cn = (c + 1) & 15;
        const unsigned* src = kpb + ((size_t)cn * 64 + sr) * D_HEAD + sd;
        #pragma unroll
        for (int g = 0; g < 4; ++g) *(uint4*)&u[g * 4] = *(const uint4*)&src[g * 4];

        f32x4 acc[2][4];
        score_from_lds(KHL[cur][0], KHL[cur][1], l15, l4, qh, ql, acc);

        #pragma unroll
        for (int st = 0; st < 2; ++st)
            #pragma unroll
            for (int r = 0; r < 4; ++r) {
                const float a0 = acc[st][0][r], a1 = acc[st][1][r];
                const float a2 = acc[st][2][r], a3 = acc[st][3][r];
                mloc[st][r] = fmaxf(mloc[st][r], fmaxf(fmaxf(a0, a1), fmaxf(a2, a3)));
                zloc[st][r] += (__expf(a0) + __expf(a1)) + (__expf(a2) + __expf(a3));
            }

        bf16x8 h0, l0, h1, l1;
        unpack_pair(&u[0], h0, l0);
        unpack_pair(&u[8], h1, l1);
        const int nxt = cur ^ 1;
        *(bf16x8*)&KHL[nxt][0][sr][sd]     = h0;
        *(bf16x8*)&KHL[nxt][0][sr][sd + 8] = h1;
        *(bf16x8*)&KHL[nxt][1][sr][sd]     = l0;
        *(bf16x8*)&KHL[nxt][1][sr][sd + 8] = l1;
        __syncthreads();
        cur = nxt;
    }

    float taue[2][4];
    bool  unif[2][4];
    int mynu = 0;
    #pragma unroll
    for (int st = 0; st < 2; ++st)
        #pragma unroll
        for (int r = 0; r < 4; ++r) {
            float mm = mloc[st][r], zz = zloc[st][r];
            #pragma unroll
            for (int o = 1; o <= 8; o <<= 1) {
                mm = fmaxf(mm, __shfl_xor(mm, o, 16));
                zz += __shfl_xor(zz, o, 16);
            }
            const float tau = __logf(SPARSE_THRESH * zz);
            const bool uni = (mm < tau);
            unif[st][r] = uni;
            taue[st][r] = uni ? 3.0e38f : tau;
            mynu |= uni ? 0 : 1;
        }
    if (__any(mynu)) { if (lane == 0) atomicOr(&AnyNU, 1); }
    __syncthreads();
    const bool runB = (AnyNU != 0);

    float z2[2][4];
    f32x4 pv[2][4];
    #pragma unroll
    for (int st = 0; st < 2; ++st)
        #pragma unroll
        for (int r = 0; r < 4; ++r) { z2[st][r] = 0.f; pv[st][r] = (f32x4){0.f, 0.f, 0.f, 0.f}; }

    if (runB) {
        #pragma unroll 1
        for (int c = 0; c < 16; ++c) {
            unsigned u[16];
            const int cn = (c + 1) & 15;
            const unsigned* src = kpb + ((size_t)cn * 64 + sr) * D_HEAD + sd;
            #pragma unroll
            for (int g = 0; g < 4; ++g) *(uint4*)&u[g * 4] = *(const uint4*)&src[g * 4];

            f32x4 acc[2][4];
            score_from_lds(KHL[cur][0], KHL[cur][1], l15, l4, qh, ql, acc);  // bit-identical

            int any = 0;
            #pragma unroll
            for (int st = 0; st < 2; ++st)
                #pragma unroll
                for (int r = 0; r < 4; ++r) {
                    const float rmax = fmaxf(fmaxf(acc[st][0][r], acc[st][1][r]),
                                             fmaxf(acc[st][2][r], acc[st][3][r]));
                    any |= (rmax >= taue[st][r]) ? 1 : 0;
                }

            if (__any(any)) {
                #pragma unroll
                for (int st = 0; st < 2; ++st)
                    #pragma unroll
                    for (int j = 0; j < 4; ++j)
                        #pragma unroll
                        for (int r = 0; r < 4; ++r) {
                            const float a = acc[st][j][r];
                            const float w = (a >= taue[st][r]) ? __expf(a) : 0.f;
                            const unsigned short wb = f2bf_rne(w);
                            z2[st][r] += bf2f(wb);
                            Wl[wv][st * 16 + l4 * 4 + r][l15 + 16 * j] = wb;
                        }
                asm volatile("s_waitcnt lgkmcnt(0)" ::: "memory");
                __builtin_amdgcn_sched_barrier(0);

                bf16x8 wa[2][2];
                #pragma unroll
                for (int st = 0; st < 2; ++st)
                    #pragma unroll
                    for (int ks = 0; ks < 2; ++ks)
                        wa[st][ks] = *(const bf16x8*)&Wl[wv][st * 16 + l15][ks * 32 + l4 * 8];

                #pragma unroll
                for (int ds = 0; ds < 4; ++ds) {
                    const bf16x8 v0 = *(const bf16x8*)
                        &vtb[(size_t)(ds * 16 + l15) * SEQ + c * 64 + l4 * 8];
                    const bf16x8 v1 = *(const bf16x8*)
                        &vtb[(size_t)(ds * 16 + l15) * SEQ + c * 64 + 32 + l4 * 8];
                    #pragma unroll
                    for (int st = 0; st < 2; ++st) {
                        pv[st][ds] = __builtin_amdgcn_mfma_f32_16x16x32_bf16(wa[st][0], v0, pv[st][ds], 0, 0, 0);
                        pv[st][ds] = __builtin_amdgcn_mfma_f32_16x16x32_bf16(wa[st][1], v1, pv[st][ds], 0, 0, 0);
                    }
                }
            }

            bf16x8 h0, l0, h1, l1;
            unpack_pair(&u[0], h0, l0);
            unpack_pair(&u[8], h1, l1);
            const int nxt = cur ^ 1;
            *(bf16x8*)&KHL[nxt][0][sr][sd]     = h0;
            *(bf16x8*)&KHL[nxt][0][sr][sd + 8] = h1;
            *(bf16x8*)&KHL[nxt][1][sr][sd]     = l0;
            *(bf16x8*)&KHL[nxt][1][sr][sd + 8] = l1;
            __syncthreads();
            cur = nxt;
        }

        #pragma unroll
        for (int st = 0; st < 2; ++st)
            #pragma unroll
            for (int r = 0; r < 4; ++r) {
                #pragma unroll
                for (int o = 1; o <= 8; o <<= 1) z2[st][r] += __shfl_xor(z2[st][r], o, 16);
            }
    }

    float* Tw = (float*)&KHL[0][0][0][0] + wv * 2176;   // per-wave [32][68] f32
    #pragma unroll
    for (int st = 0; st < 2; ++st)
        #pragma unroll
        for (int r = 0; r < 4; ++r) {
            const float inv = unif[st][r] ? 0.f : (1.f / z2[st][r]);
            const int row = st * 16 + l4 * 4 + r;
            #pragma unroll
            for (int ds = 0; ds < 4; ++ds) {
                const int d = ds * 16 + l15;
                Tw[row * 68 + d] = unif[st][r] ? Vm[d] : pv[st][ds][r] * inv;
            }
        }
    asm volatile("s_waitcnt lgkmcnt(0)" ::: "memory");
    __builtin_amdgcn_sched_barrier(0);

    const int rr = lane >> 1, seg = lane & 1;
    const size_t gbase = ((size_t)b * SEQ + q0 + rr) * D_MODEL + h * D_HEAD + seg * 32;
    #pragma unroll
    for (int u2 = 0; u2 < 8; ++u2) {
        const float4 t = *(const float4*)&Tw[rr * 68 + seg * 32 + u2 * 4];
        unsigned short h4[4] = {f2bf_rne(t.x), f2bf_rne(t.y), f2bf_rne(t.z), f2bf_rne(t.w)};
        *(uint2*)&ctxh[gbase + u2 * 4] = *(const uint2*)h4;
    }
}

extern "C" void kernel_launch(void* const* d_in, const int* in_sizes, int n_in,
                              void* d_out, int out_size, void* d_ws, size_t ws_size,
                              hipStream_t stream)
{
    const float* q  = (const float*)d_in[0];
    const float* k  = (const float*)d_in[1];
    const float* v  = (const float*)d_in[2];
    const float* Wq = (const float*)d_in[3];
    const float* bq = (const float*)d_in[4];
    const float* Wk = (const float*)d_in[5];
    const float* bk = (const float*)d_in[6];
    const float* Wv = (const float*)d_in[7];
    const float* bv = (const float*)d_in[8];
    const float* Wo = (const float*)d_in[9];
    const float* bo = (const float*)d_in[10];
    float* out = (float*)d_out;

    // workspace (60 MiB): qp 16 + kp 16 + vt 8 + ctxh 8 + 6 weight planes (12)
    const size_t MB = 1 << 20;
    char* w = (char*)d_ws;
    unsigned* qp = (unsigned*)(w);
    unsigned* kp = (unsigned*)(w + 16 * MB);
    unsigned short* vt   = (unsigned short*)(w + 32 * MB);
    unsigned short* ctxh = (unsigned short*)(w + 40 * MB);
    unsigned short* Wqh = (unsigned short*)(w + 48 * MB);
    unsigned short* Wql = (unsigned short*)(w + 50 * MB);
    unsigned short* Wkh = (unsigned short*)(w + 52 * MB);
    unsigned short* Wkl = (unsigned short*)(w + 54 * MB);
    unsigned short* Wvh = (unsigned short*)(w + 56 * MB);
    unsigned short* Wvl = (unsigned short*)(w + 58 * MB);

    const int NW8 = (D_MODEL * D_MODEL) / 8;      // 131072

    // pre-split the 3 weight matrices (removes 32x-redundant in-loop W conversion)
    conv_w<<<(3 * NW8) / 256, 256, 0, stream>>>(Wq, Wk, Wv, Wqh, Wql, Wkh, Wkl, Wvh, Wvl);

    // fused Q/K/V: grid (32,8,3), x=bm -> id%8 = bm%8 (A-row XCD locality)
    proj_qkv<<<dim3(32, 8, 3), 256, 0, stream>>>(q, k, v,
                                                 Wqh, Wql, Wkh, Wkl, Wvh, Wvl,
                                                 bq, bk, bv, qp, kp, vt);

    // bh on x: all 8 q-blocks of a (b,h) share an XCD (id%8 = bh%8)
    attn_mfma<<<dim3(BATCH * N_HEADS, SEQ / 128), 256, 0, stream>>>(qp, kp, vt, ctxh);

    proj_o<<<dim3(32, 8), 256, 0, stream>>>(ctxh, Wo, bo, out);
}

// Round 20
// 175.374 us; speedup vs baseline: 1.0448x; 1.0162x over previous
//
#include <hip/hip_runtime.h>
#include <hip/hip_bf16.h>
#include <math.h>

// Sparse MHA encoder: B=4, S=1024, D=1024, H=16, dk=64.
// Numerics: the 0.09 threshold is a step function on first-pass softmax.
// Score path (Q/K projections + QK^T) is split-bf16 (hi+lo, ~2^-18 rel err)
// -> E[mask flips] ~1e-4. Post-mask paths (PV, ctx, O-proj) direct bf16.
// Pass B recomputes scores BIT-IDENTICALLY to pass A (same helper, same LDS).
// Uniform-row skip: row all-masked <=> rowmax < tau = log(0.09*Z).
// R20: attn -> 512 threads / 8 waves x 16q (was 4 waves x 32q). Same grid
// (512 blocks), same LDS (2 blocks/CU), same barrier structure and memory
// traffic -- but 16 waves/CU = 4 waves/SIMD (was 2): doubles what the SIMD
// can interleave across the lockstep chunk chains. This is the one TLP lever
// the three staging nulls (R16-R18) never touched.

constexpr int D_MODEL = 1024;
constexpr int N_HEADS = 16;
constexpr int D_HEAD  = 64;
constexpr int SEQ     = 1024;
constexpr int BATCH   = 4;
constexpr float SPARSE_THRESH = 0.09f;

typedef short  bf16x8 __attribute__((ext_vector_type(8)));
typedef float  f32x4  __attribute__((ext_vector_type(4)));

__device__ __forceinline__ unsigned short f2bf_rne(float x) {
    unsigned u = __float_as_uint(x);
    u += 0x7FFFu + ((u >> 16) & 1u);          // round-to-nearest-even
    return (unsigned short)(u >> 16);
}
__device__ __forceinline__ float bf2f(unsigned short b) {
    return __uint_as_float(((unsigned)b) << 16);
}

// packed RNE pair-convert: low16 = bf16(a), high16 = bf16(b)  (v_cvt_pk_bf16_f32)
__device__ __forceinline__ unsigned cvt2(float a, float b) {
    __hip_bfloat162 p = __float22bfloat162_rn(make_float2(a, b));
    unsigned u; __builtin_memcpy(&u, &p, 4); return u;
}
// split 4 floats -> 2 packed hi words + 2 packed lo words
__device__ __forceinline__ void split4(float x0, float x1, float x2, float x3,
                                       unsigned* hw, unsigned* lw) {
    const unsigned uh0 = cvt2(x0, x1);
    hw[0] = uh0;
    lw[0] = cvt2(x0 - __uint_as_float(uh0 << 16),
                 x1 - __uint_as_float(uh0 & 0xFFFF0000u));
    const unsigned uh1 = cvt2(x2, x3);
    hw[1] = uh1;
    lw[1] = cvt2(x2 - __uint_as_float(uh1 << 16),
                 x3 - __uint_as_float(uh1 & 0xFFFF0000u));
}

union BF8 { unsigned u[4]; bf16x8 v; };

// 8 packed words (hi<<16|lo) -> hi bf16x8 + lo bf16x8
__device__ __forceinline__ void unpack_pair(const unsigned* u, bf16x8& hi, bf16x8& lo) {
    BF8 h, l;
    #pragma unroll
    for (int p = 0; p < 4; ++p) {
        h.u[p] = (u[2 * p] >> 16)      | (u[2 * p + 1] & 0xFFFF0000u);
        l.u[p] = (u[2 * p] & 0xFFFFu)  | (u[2 * p + 1] << 16);
    }
    hi = h.v; lo = l.v;
}

// ============ weight pre-split: Wq/Wk/Wv -> hi/lo bf16 planes ============
__global__ __launch_bounds__(256)
void conv_w(const float* __restrict__ Wq, const float* __restrict__ Wk,
            const float* __restrict__ Wv,
            unsigned short* __restrict__ Wqh, unsigned short* __restrict__ Wql,
            unsigned short* __restrict__ Wkh, unsigned short* __restrict__ Wkl,
            unsigned short* __restrict__ Wvh, unsigned short* __restrict__ Wvl)
{
    const int NW8 = (D_MODEL * D_MODEL) / 8;      // 131072
    int i = blockIdx.x * 256 + threadIdx.x;
    const float* s; unsigned short *dh, *dl;
    if (i < NW8)            { s = Wq; dh = Wqh; dl = Wql; }
    else if (i < 2 * NW8)   { i -= NW8; s = Wk; dh = Wkh; dl = Wkl; }
    else                    { i -= 2 * NW8; s = Wv; dh = Wvh; dl = Wvl; }
    const float4 x0 = ((const float4*)(s + (size_t)i * 8))[0];
    const float4 x1 = ((const float4*)(s + (size_t)i * 8))[1];
    unsigned hw[4], lw[4];
    split4(x0.x, x0.y, x0.z, x0.w, &hw[0], &lw[0]);
    split4(x1.x, x1.y, x1.z, x1.w, &hw[2], &lw[2]);
    *(uint4*)&dh[(size_t)i * 8] = *(const uint4*)hw;
    *(uint4*)&dl[(size_t)i * 8] = *(const uint4*)lw;
}

// ============ fused Q/K/V projection (256 thr, 64x64/wave) ============
// z selects {Q,K,V}. A (input) split in-loop via cvt_pk; W pre-split planes.
// z<2: packed u32 (hi<<16|lo) head-split [B,H,S,dk], scaled (Q: 1/8).
// z==2: bf16 plane TRANSPOSED [B,H,dk,S] via LDS bounce, 256B-run stores.
// Grid (32,8,3): x=bm -> id%8 = bm%8 (A-row XCD locality).
__global__ __launch_bounds__(256, 3)
void proj_qkv(const float* __restrict__ q, const float* __restrict__ k,
              const float* __restrict__ v,
              const unsigned short* __restrict__ Wqh, const unsigned short* __restrict__ Wql,
              const unsigned short* __restrict__ Wkh, const unsigned short* __restrict__ Wkl,
              const unsigned short* __restrict__ Wvh, const unsigned short* __restrict__ Wvl,
              const float* __restrict__ bq, const float* __restrict__ bk,
              const float* __restrict__ bv,
              unsigned* __restrict__ qp, unsigned* __restrict__ kp,
              unsigned short* __restrict__ vt)
{
    __shared__ unsigned short SM[4][128][40];   // A_h, A_l, B_h, B_l
    unsigned short (*A_h)[40] = SM[0];
    unsigned short (*A_l)[40] = SM[1];
    unsigned short (*B_h)[40] = SM[2];
    unsigned short (*B_l)[40] = SM[3];

    const int z = blockIdx.z;
    const float* X    = (z == 0) ? q   : (z == 1) ? k   : v;
    const unsigned short* Wh = (z == 0) ? Wqh : (z == 1) ? Wkh : Wvh;
    const unsigned short* Wl = (z == 0) ? Wql : (z == 1) ? Wkl : Wvl;
    const float* bias = (z == 0) ? bq  : (z == 1) ? bk  : bv;
    const float scale = (z == 0) ? 0.125f : 1.0f;

    const int K = D_MODEL;
    const int tid = threadIdx.x, lane = tid & 63;
    const int l15 = lane & 15, l4 = lane >> 4;
    const int wv4 = tid >> 6;
    const int wr = (wv4 >> 1) * 64, wc = (wv4 & 1) * 64;
    const int bm = blockIdx.x * 128, bn = blockIdx.y * 128;   // x=bm (XCD locality)
    const int sr = tid >> 1, sh = (tid & 1) * 16;

    f32x4 acc[4][4];
    #pragma unroll
    for (int i = 0; i < 4; ++i)
        #pragma unroll
        for (int j = 0; j < 4; ++j) acc[i][j] = (f32x4){0.f, 0.f, 0.f, 0.f};

    const float* ga = X + (size_t)(bm + sr) * K + sh;
    const unsigned short* gbh = Wh + (size_t)(bn + sr) * K + sh;
    const unsigned short* gbl = Wl + (size_t)(bn + sr) * K + sh;

    float4 av[4];
    uint4 wbh0, wbh1, wbl0, wbl1;
    #pragma unroll
    for (int l = 0; l < 4; ++l) av[l] = *(const float4*)&ga[l * 4];
    wbh0 = *(const uint4*)&gbh[0]; wbh1 = *(const uint4*)&gbh[8];
    wbl0 = *(const uint4*)&gbl[0]; wbl1 = *(const uint4*)&gbl[8];

    #pragma unroll 1
    for (int k0 = 0; k0 < K; k0 += 32) {
        // split A (cvt_pk path: ~3 VALU/value; productive latency filler)
        unsigned ahw[8], alw[8];
        #pragma unroll
        for (int l = 0; l < 4; ++l)
            split4(av[l].x, av[l].y, av[l].z, av[l].w, &ahw[l * 2], &alw[l * 2]);

        __syncthreads();                 // prior frag reads done
        *(uint4*)&A_h[sr][sh]     = *(const uint4*)&ahw[0];
        *(uint4*)&A_h[sr][sh + 8] = *(const uint4*)&ahw[4];
        *(uint4*)&A_l[sr][sh]     = *(const uint4*)&alw[0];
        *(uint4*)&A_l[sr][sh + 8] = *(const uint4*)&alw[4];
        *(uint4*)&B_h[sr][sh]     = wbh0;
        *(uint4*)&B_h[sr][sh + 8] = wbh1;
        *(uint4*)&B_l[sr][sh]     = wbl0;
        *(uint4*)&B_l[sr][sh + 8] = wbl1;
        __syncthreads();                 // tiles ready

        if (k0 + 32 < K) {               // issue next-step loads under MFMA
            const int o = k0 + 32;
            #pragma unroll
            for (int l = 0; l < 4; ++l) av[l] = *(const float4*)&ga[o + l * 4];
            wbh0 = *(const uint4*)&gbh[o]; wbh1 = *(const uint4*)&gbh[o + 8];
            wbl0 = *(const uint4*)&gbl[o]; wbl1 = *(const uint4*)&gbl[o + 8];
        }

        bf16x8 ah[4], al4[4], bh4[4], bl4[4];
        #pragma unroll
        for (int i = 0; i < 4; ++i) {
            const int r = wr + i * 16 + l15;
            const int c = wc + i * 16 + l15;
            ah[i]  = *(const bf16x8*)&A_h[r][l4 * 8];
            al4[i] = *(const bf16x8*)&A_l[r][l4 * 8];
            bh4[i] = *(const bf16x8*)&B_h[c][l4 * 8];
            bl4[i] = *(const bf16x8*)&B_l[c][l4 * 8];
        }
        #pragma unroll
        for (int i = 0; i < 4; ++i)
            #pragma unroll
            for (int j = 0; j < 4; ++j) {
                acc[i][j] = __builtin_amdgcn_mfma_f32_16x16x32_bf16(ah[i],  bh4[j], acc[i][j], 0, 0, 0);
                acc[i][j] = __builtin_amdgcn_mfma_f32_16x16x32_bf16(ah[i],  bl4[j], acc[i][j], 0, 0, 0);
                acc[i][j] = __builtin_amdgcn_mfma_f32_16x16x32_bf16(al4[i], bh4[j], acc[i][j], 0, 0, 0);
            }
    }

    if (z == 2) {
        // V: transpose bounce -> vt[B,H,dk,S]; 256B-run coalesced stores
        unsigned short* T = &SM[0][0][0];            // [128][136]
        __syncthreads();
        #pragma unroll
        for (int i = 0; i < 4; ++i)
            #pragma unroll
            for (int j = 0; j < 4; ++j) {
                const int cl = wc + j * 16 + l15;
                const int sl = wr + i * 16 + l4 * 4;
                const float bi = bias[bn + cl];
                unsigned short h4[4];
                #pragma unroll
                for (int r = 0; r < 4; ++r)
                    h4[r] = f2bf_rne(acc[i][j][r] + bi);
                *(uint2*)&T[cl * 136 + sl] = *(const uint2*)&h4[0];
            }
        __syncthreads();
        const int c = tid >> 1, half = tid & 1;
        const int bb = bm >> 10;
        const int sb = (bm & (SEQ - 1)) + half * 64;
        unsigned short* dst = vt + (((size_t)bb << 20) + (size_t)(bn + c) * SEQ + sb);
        const unsigned short* srcT = &T[c * 136 + half * 64];
        #pragma unroll
        for (int u = 0; u < 8; ++u)
            *(uint4*)&dst[u * 8] = *(const uint4*)&srcT[u * 8];
        return;
    }

    // Q/K: packed u32, head-split
    unsigned* Cp = (z == 0) ? qp : kp;
    #pragma unroll
    for (int i = 0; i < 4; ++i)
        #pragma unroll
        for (int j = 0; j < 4; ++j) {
            const int rb = bm + wr + i * 16 + l4 * 4;
            const int c  = bn + wc + j * 16 + l15;
            const float bi = bias[c];
            const int h = c >> 6, d = c & (D_HEAD - 1);
            #pragma unroll
            for (int r = 0; r < 4; ++r) {
                const float val = (acc[i][j][r] + bi) * scale;
                const unsigned short hu = f2bf_rne(val);
                const unsigned short lu = f2bf_rne(val - bf2f(hu));
                const int mrow = rb + r;
                const int b = mrow >> 10, s = mrow & (SEQ - 1);
                Cp[((size_t)(b * N_HEADS + h) * SEQ + s) * D_HEAD + d] =
                    ((unsigned)hu << 16) | lu;
            }
        }
}

// ============ O projection: bf16 ctx plane x hi(Wo), fp32 out ============
__global__ __launch_bounds__(256, 3)
void proj_o(const unsigned short* __restrict__ Act, const float* __restrict__ W,
            const float* __restrict__ bias, float* __restrict__ out)
{
    __shared__ unsigned short A_h[128][40];
    __shared__ unsigned short B_h[128][40];

    const int K = D_MODEL;
    const int tid = threadIdx.x, lane = tid & 63;
    const int l15 = lane & 15, l4 = lane >> 4;
    const int wv4 = tid >> 6;
    const int wr = (wv4 >> 1) * 64, wc = (wv4 & 1) * 64;
    const int bm = blockIdx.x * 128, bn = blockIdx.y * 128;
    const int sr = tid >> 1, sh = (tid & 1) * 16;

    f32x4 acc[4][4];
    #pragma unroll
    for (int i = 0; i < 4; ++i)
        #pragma unroll
        for (int j = 0; j < 4; ++j) acc[i][j] = (f32x4){0.f, 0.f, 0.f, 0.f};

    const unsigned short* ga = Act + (size_t)(bm + sr) * K + sh;
    const float* gb = W + (size_t)(bn + sr) * K + sh;

    uint4 av0 = *(const uint4*)&ga[0], av1 = *(const uint4*)&ga[8];
    float4 bv4[4];
    #pragma unroll
    for (int l = 0; l < 4; ++l) bv4[l] = *(const float4*)&gb[l * 4];

    #pragma unroll 1
    for (int k0 = 0; k0 < K; k0 += 32) {
        unsigned bhw[8];
        #pragma unroll
        for (int l = 0; l < 4; ++l) {
            bhw[l * 2]     = cvt2(bv4[l].x, bv4[l].y);
            bhw[l * 2 + 1] = cvt2(bv4[l].z, bv4[l].w);
        }

        __syncthreads();
        *(uint4*)&A_h[sr][sh]     = av0;
        *(uint4*)&A_h[sr][sh + 8] = av1;
        *(uint4*)&B_h[sr][sh]     = *(const uint4*)&bhw[0];
        *(uint4*)&B_h[sr][sh + 8] = *(const uint4*)&bhw[4];
        __syncthreads();

        if (k0 + 32 < K) {
            av0 = *(const uint4*)&ga[k0 + 32];
            av1 = *(const uint4*)&ga[k0 + 32 + 8];
            #pragma unroll
            for (int l = 0; l < 4; ++l)
                bv4[l] = *(const float4*)&gb[k0 + 32 + l * 4];
        }

        bf16x8 ah[4], bh4[4];
        #pragma unroll
        for (int i = 0; i < 4; ++i) {
            ah[i]  = *(const bf16x8*)&A_h[wr + i * 16 + l15][l4 * 8];
            bh4[i] = *(const bf16x8*)&B_h[wc + i * 16 + l15][l4 * 8];
        }
        #pragma unroll
        for (int i = 0; i < 4; ++i)
            #pragma unroll
            for (int j = 0; j < 4; ++j)
                acc[i][j] = __builtin_amdgcn_mfma_f32_16x16x32_bf16(ah[i], bh4[j], acc[i][j], 0, 0, 0);
    }

    #pragma unroll
    for (int i = 0; i < 4; ++i)
        #pragma unroll
        for (int j = 0; j < 4; ++j) {
            const int rb = bm + wr + i * 16 + l4 * 4;
            const int c  = bn + wc + j * 16 + l15;
            const float bi = bias[c];
            #pragma unroll
            for (int r = 0; r < 4; ++r)
                out[(size_t)(rb + r) * D_MODEL + c] = acc[i][j][r] + bi;
        }
}

// ============ MFMA attention (8 waves x 16q, 4 waves/SIMD) ============
__device__ __forceinline__ void score16(
    const unsigned short (* __restrict__ KH)[72], const unsigned short (* __restrict__ KL)[72],
    int l15, int l4, const bf16x8 (&qh)[2], const bf16x8 (&ql)[2], f32x4 acc[4])
{
    #pragma unroll
    for (int j = 0; j < 4; ++j) {
        const int row = l15 + 16 * j;
        const bf16x8 kh0 = *(const bf16x8*)&KH[row][l4 * 8];
        const bf16x8 kh1 = *(const bf16x8*)&KH[row][32 + l4 * 8];
        const bf16x8 kl0 = *(const bf16x8*)&KL[row][l4 * 8];
        const bf16x8 kl1 = *(const bf16x8*)&KL[row][32 + l4 * 8];
        f32x4 a = (f32x4){0.f, 0.f, 0.f, 0.f};
        a = __builtin_amdgcn_mfma_f32_16x16x32_bf16(qh[0], kh0, a, 0, 0, 0);
        a = __builtin_amdgcn_mfma_f32_16x16x32_bf16(qh[0], kl0, a, 0, 0, 0);
        a = __builtin_amdgcn_mfma_f32_16x16x32_bf16(ql[0], kh0, a, 0, 0, 0);
        a = __builtin_amdgcn_mfma_f32_16x16x32_bf16(qh[1], kh1, a, 0, 0, 0);
        a = __builtin_amdgcn_mfma_f32_16x16x32_bf16(qh[1], kl1, a, 0, 0, 0);
        a = __builtin_amdgcn_mfma_f32_16x16x32_bf16(ql[1], kh1, a, 0, 0, 0);
        acc[j] = a;
    }
}

__global__ __launch_bounds__(512, 4)
void attn_mfma(const unsigned* __restrict__ qp, const unsigned* __restrict__ kp,
               const unsigned short* __restrict__ vt, unsigned short* __restrict__ ctxh)
{
    __shared__ unsigned short KHL[2][2][64][72];   // 36864 B
    __shared__ unsigned short Wl[8][16][64];       // 16384 B, per-wave W [q][k]
    __shared__ float Vm[64];
    __shared__ int AnyNU;
    // Pm aliased into Wl: Pm dead after Vm (prologue barrier); Wl used in pass B.
    float (*Pm)[8] = (float (*)[8])&Wl[0][0][0];   // [64][8] f32 = 2KB

    const int tid  = threadIdx.x;
    const int lane = tid & 63;
    const int wv   = tid >> 6;                     // 0..7
    const int l15  = lane & 15, l4 = lane >> 4;
    const int bh   = blockIdx.x;                   // XCD locality: id%8 = bh%8
    const int b    = bh >> 4, h = bh & 15;
    const int q0   = blockIdx.y * 128 + wv * 16;   // 16 q per wave

    // ---- Q fragments (packed -> hi/lo), 16 rows ----
    bf16x8 qh[2], ql[2];
    {
        const unsigned* qrow = qp + ((size_t)bh * SEQ + q0 + l15) * D_HEAD;
        #pragma unroll
        for (int ks = 0; ks < 2; ++ks) {
            unsigned u[8];
            *(uint4*)&u[0] = *(const uint4*)&qrow[ks * 32 + l4 * 8];
            *(uint4*)&u[4] = *(const uint4*)&qrow[ks * 32 + l4 * 8 + 4];
            unpack_pair(u, qh[ks], ql[ks]);
        }
    }

    const unsigned short* vtb = vt + (size_t)bh * D_HEAD * SEQ;

    // ---- vmean partials: thread t sums 128 V values of row d = t>>3 ----
    {
        const int d = tid >> 3, q8 = tid & 7;
        const unsigned short* vr = vtb + (size_t)d * SEQ + q8 * 128;
        float s0 = 0.f, s1 = 0.f, s2 = 0.f, s3 = 0.f;
        #pragma unroll 4
        for (int i = 0; i < 16; ++i) {
            bf16x8 v8 = *(const bf16x8*)&vr[i * 8];
            s0 += bf2f((unsigned short)v8[0]) + bf2f((unsigned short)v8[4]);
            s1 += bf2f((unsigned short)v8[1]) + bf2f((unsigned short)v8[5]);
            s2 += bf2f((unsigned short)v8[2]) + bf2f((unsigned short)v8[6]);
            s3 += bf2f((unsigned short)v8[3]) + bf2f((unsigned short)v8[7]);
        }
        Pm[d][q8] = (s0 + s1) + (s2 + s3);
        if (tid == 0) AnyNU = 0;
    }

    // staging: 512 threads cover 64 k-rows x 64 words; sr = tid>>3, sd = (tid&7)*8
    const int sr = tid >> 3;
    const int sd = (tid & 7) * 8;
    const unsigned* kpb = kp + (size_t)bh * SEQ * D_HEAD;

    {   // prologue: stage chunk 0 -> buf 0
        unsigned u[8];
        const unsigned* src = kpb + (size_t)sr * D_HEAD + sd;
        *(uint4*)&u[0] = *(const uint4*)&src[0];
        *(uint4*)&u[4] = *(const uint4*)&src[4];
        bf16x8 h0, l0;
        unpack_pair(u, h0, l0);
        *(bf16x8*)&KHL[0][0][sr][sd] = h0;
        *(bf16x8*)&KHL[0][1][sr][sd] = l0;
    }
    __syncthreads();

    if (tid < 64)
        Vm[tid] = (((Pm[tid][0] + Pm[tid][1]) + (Pm[tid][2] + Pm[tid][3]))
                 + ((Pm[tid][4] + Pm[tid][5]) + (Pm[tid][6] + Pm[tid][7]))) * (1.f / 1024.f);

    float mloc[4], zloc[4];
    #pragma unroll
    for (int r = 0; r < 4; ++r) { mloc[r] = -1e30f; zloc[r] = 0.f; }

    int cur = 0;

    // ========== pass A: Z = sum(e^s), m = max(s) ==========
    #pragma unroll 1
    for (int c = 0; c < 16; ++c) {
        unsigned u[8];                              // stage next chunk (issue early)
        const int cn = (c + 1) & 15;
        const unsigned* src = kpb + ((size_t)cn * 64 + sr) * D_HEAD + sd;
        *(uint4*)&u[0] = *(const uint4*)&src[0];
        *(uint4*)&u[4] = *(const uint4*)&src[4];

        f32x4 acc[4];
        score16(KHL[cur][0], KHL[cur][1], l15, l4, qh, ql, acc);

        #pragma unroll
        for (int r = 0; r < 4; ++r) {
            const float a0 = acc[0][r], a1 = acc[1][r];
            const float a2 = acc[2][r], a3 = acc[3][r];
            mloc[r] = fmaxf(mloc[r], fmaxf(fmaxf(a0, a1), fmaxf(a2, a3)));
            zloc[r] += (__expf(a0) + __expf(a1)) + (__expf(a2) + __expf(a3));
        }

        bf16x8 h0, l0;                              // write staged chunk (late)
        unpack_pair(u, h0, l0);
        const int nxt = cur ^ 1;
        *(bf16x8*)&KHL[nxt][0][sr][sd] = h0;
        *(bf16x8*)&KHL[nxt][1][sr][sd] = l0;
        __syncthreads();
        cur = nxt;
    }

    // ---- merge over 16-lane col groups; tau test; uniform detect ----
    float taue[4];
    bool  unif[4];
    int mynu = 0;
    #pragma unroll
    for (int r = 0; r < 4; ++r) {
        float mm = mloc[r], zz = zloc[r];
        #pragma unroll
        for (int o = 1; o <= 8; o <<= 1) {
            mm = fmaxf(mm, __shfl_xor(mm, o, 16));
            zz += __shfl_xor(zz, o, 16);
        }
        const float tau = __logf(SPARSE_THRESH * zz);
        const bool uni = (mm < tau);
        unif[r] = uni;
        taue[r] = uni ? 3.0e38f : tau;
        mynu |= uni ? 0 : 1;
    }
    if (__any(mynu)) { if (lane == 0) atomicOr(&AnyNU, 1); }
    __syncthreads();
    const bool runB = (AnyNU != 0);

    float z2[4];
    f32x4 pv[4];
    #pragma unroll
    for (int r = 0; r < 4; ++r) { z2[r] = 0.f; pv[r] = (f32x4){0.f, 0.f, 0.f, 0.f}; }

    // ========== pass B: only if a non-uniform row exists ==========
    if (runB) {
        #pragma unroll 1
        for (int c = 0; c < 16; ++c) {
            unsigned u[8];
            const int cn = (c + 1) & 15;
            const unsigned* src = kpb + ((size_t)cn * 64 + sr) * D_HEAD + sd;
            *(uint4*)&u[0] = *(const uint4*)&src[0];
            *(uint4*)&u[4] = *(const uint4*)&src[4];

            f32x4 acc[4];
            score16(KHL[cur][0], KHL[cur][1], l15, l4, qh, ql, acc);   // bit-identical

            int any = 0;
            #pragma unroll
            for (int r = 0; r < 4; ++r) {
                const float rmax = fmaxf(fmaxf(acc[0][r], acc[1][r]),
                                         fmaxf(acc[2][r], acc[3][r]));
                any |= (rmax >= taue[r]) ? 1 : 0;
            }

            if (__any(any)) {
                #pragma unroll
                for (int j = 0; j < 4; ++j)
                    #pragma unroll
                    for (int r = 0; r < 4; ++r) {
                        const float a = acc[j][r];
                        const float w = (a >= taue[r]) ? __expf(a) : 0.f;
                        const unsigned short wb = f2bf_rne(w);
                        z2[r] += bf2f(wb);
                        Wl[wv][l4 * 4 + r][l15 + 16 * j] = wb;
                    }
                asm volatile("s_waitcnt lgkmcnt(0)" ::: "memory");
                __builtin_amdgcn_sched_barrier(0);

                bf16x8 wa[2];
                #pragma unroll
                for (int ks = 0; ks < 2; ++ks)
                    wa[ks] = *(const bf16x8*)&Wl[wv][l15][ks * 32 + l4 * 8];

                #pragma unroll
                for (int ds = 0; ds < 4; ++ds) {
                    const bf16x8 v0 = *(const bf16x8*)
                        &vtb[(size_t)(ds * 16 + l15) * SEQ + c * 64 + l4 * 8];
                    const bf16x8 v1 = *(const bf16x8*)
                        &vtb[(size_t)(ds * 16 + l15) * SEQ + c * 64 + 32 + l4 * 8];
                    pv[ds] = __builtin_amdgcn_mfma_f32_16x16x32_bf16(wa[0], v0, pv[ds], 0, 0, 0);
                    pv[ds] = __builtin_amdgcn_mfma_f32_16x16x32_bf16(wa[1], v1, pv[ds], 0, 0, 0);
                }
            }

            bf16x8 h0, l0;
            unpack_pair(u, h0, l0);
            const int nxt = cur ^ 1;
            *(bf16x8*)&KHL[nxt][0][sr][sd] = h0;
            *(bf16x8*)&KHL[nxt][1][sr][sd] = l0;
            __syncthreads();
            cur = nxt;
        }

        #pragma unroll
        for (int r = 0; r < 4; ++r) {
            #pragma unroll
            for (int o = 1; o <= 8; o <<= 1) z2[r] += __shfl_xor(z2[r], o, 16);
        }
    }

    // ---- epilogue: select vmean vs pv/z2; per-wave bounce [16][68] f32 ----
    float* Tw = (float*)&KHL[0][0][0][0] + wv * 1088;   // 16*68 = 1088 f32/wave
    #pragma unroll
    for (int r = 0; r < 4; ++r) {
        const float inv = unif[r] ? 0.f : (1.f / z2[r]);
        const int row = l4 * 4 + r;
        #pragma unroll
        for (int ds = 0; ds < 4; ++ds) {
            const int d = ds * 16 + l15;
            Tw[row * 68 + d] = unif[r] ? Vm[d] : pv[ds][r] * inv;
        }
    }
    asm volatile("s_waitcnt lgkmcnt(0)" ::: "memory");
    __builtin_amdgcn_sched_barrier(0);

    // lane -> row rr = lane>>2 (16 rows), seg = lane&3 (16 f32 each)
    const int rr = lane >> 2, seg = lane & 3;
    const size_t gbase = ((size_t)b * SEQ + q0 + rr) * D_MODEL + h * D_HEAD + seg * 16;
    #pragma unroll
    for (int u2 = 0; u2 < 4; ++u2) {
        const float4 t = *(const float4*)&Tw[rr * 68 + seg * 16 + u2 * 4];
        unsigned short h4[4] = {f2bf_rne(t.x), f2bf_rne(t.y), f2bf_rne(t.z), f2bf_rne(t.w)};
        *(uint2*)&ctxh[gbase + u2 * 4] = *(const uint2*)h4;
    }
}

extern "C" void kernel_launch(void* const* d_in, const int* in_sizes, int n_in,
                              void* d_out, int out_size, void* d_ws, size_t ws_size,
                              hipStream_t stream)
{
    const float* q  = (const float*)d_in[0];
    const float* k  = (const float*)d_in[1];
    const float* v  = (const float*)d_in[2];
    const float* Wq = (const float*)d_in[3];
    const float* bq = (const float*)d_in[4];
    const float* Wk = (const float*)d_in[5];
    const float* bk = (const float*)d_in[6];
    const float* Wv = (const float*)d_in[7];
    const float* bv = (const float*)d_in[8];
    const float* Wo = (const float*)d_in[9];
    const float* bo = (const float*)d_in[10];
    float* out = (float*)d_out;

    // workspace (60 MiB): qp 16 + kp 16 + vt 8 + ctxh 8 + 6 weight planes (12)
    const size_t MB = 1 << 20;
    char* w = (char*)d_ws;
    unsigned* qp = (unsigned*)(w);
    unsigned* kp = (unsigned*)(w + 16 * MB);
    unsigned short* vt   = (unsigned short*)(w + 32 * MB);
    unsigned short* ctxh = (unsigned short*)(w + 40 * MB);
    unsigned short* Wqh = (unsigned short*)(w + 48 * MB);
    unsigned short* Wql = (unsigned short*)(w + 50 * MB);
    unsigned short* Wkh = (unsigned short*)(w + 52 * MB);
    unsigned short* Wkl = (unsigned short*)(w + 54 * MB);
    unsigned short* Wvh = (unsigned short*)(w + 56 * MB);
    unsigned short* Wvl = (unsigned short*)(w + 58 * MB);

    const int NW8 = (D_MODEL * D_MODEL) / 8;      // 131072

    // pre-split the 3 weight matrices (removes 32x-redundant in-loop W conversion)
    conv_w<<<(3 * NW8) / 256, 256, 0, stream>>>(Wq, Wk, Wv, Wqh, Wql, Wkh, Wkl, Wvh, Wvl);

    // fused Q/K/V: grid (32,8,3), x=bm -> id%8 = bm%8 (A-row XCD locality)
    proj_qkv<<<dim3(32, 8, 3), 256, 0, stream>>>(q, k, v,
                                                 Wqh, Wql, Wkh, Wkl, Wvh, Wvl,
                                                 bq, bk, bv, qp, kp, vt);

    // bh on x: all 8 q-blocks of a (b,h) share an XCD (id%8 = bh%8)
    attn_mfma<<<dim3(BATCH * N_HEADS, SEQ / 128), 512, 0, stream>>>(qp, kp, vt, ctxh);

    proj_o<<<dim3(32, 8), 256, 0, stream>>>(ctxh, Wo, bo, out);
}

// Round 21
// 173.197 us; speedup vs baseline: 1.0580x; 1.0126x over previous
//
#include <hip/hip_runtime.h>
#include <hip/hip_bf16.h>
#include <math.h>

// Sparse MHA encoder: B=4, S=1024, D=1024, H=16, dk=64.
// Numerics: the 0.09 threshold is a step function on first-pass softmax.
// Score path (Q/K projections + QK^T) is split-bf16 (hi+lo, ~2^-18 rel err)
// -> E[mask flips] ~1e-4. Post-mask paths (PV, ctx, O-proj) direct bf16.
// Pass B recomputes scores BIT-IDENTICALLY to pass A (same helper, same LDS).
// Uniform-row skip: row all-masked <=> rowmax < tau = log(0.09*Z).
// R21: proj_o 128x128 -> 64x128 tiles: grid (64,8) = 512 blocks = 2/CU
// (was 256 = 1/CU = 1 wave/SIMD, the R9 stall regime). Same K-loop pattern
// and conversion order -> bit-identical output. attn/proj_qkv unchanged
// from R20 (175.4us best: 8-wave attn + 3/CU proj_qkv).

constexpr int D_MODEL = 1024;
constexpr int N_HEADS = 16;
constexpr int D_HEAD  = 64;
constexpr int SEQ     = 1024;
constexpr int BATCH   = 4;
constexpr float SPARSE_THRESH = 0.09f;

typedef short  bf16x8 __attribute__((ext_vector_type(8)));
typedef float  f32x4  __attribute__((ext_vector_type(4)));

__device__ __forceinline__ unsigned short f2bf_rne(float x) {
    unsigned u = __float_as_uint(x);
    u += 0x7FFFu + ((u >> 16) & 1u);          // round-to-nearest-even
    return (unsigned short)(u >> 16);
}
__device__ __forceinline__ float bf2f(unsigned short b) {
    return __uint_as_float(((unsigned)b) << 16);
}

// packed RNE pair-convert: low16 = bf16(a), high16 = bf16(b)  (v_cvt_pk_bf16_f32)
__device__ __forceinline__ unsigned cvt2(float a, float b) {
    __hip_bfloat162 p = __float22bfloat162_rn(make_float2(a, b));
    unsigned u; __builtin_memcpy(&u, &p, 4); return u;
}
// split 4 floats -> 2 packed hi words + 2 packed lo words
__device__ __forceinline__ void split4(float x0, float x1, float x2, float x3,
                                       unsigned* hw, unsigned* lw) {
    const unsigned uh0 = cvt2(x0, x1);
    hw[0] = uh0;
    lw[0] = cvt2(x0 - __uint_as_float(uh0 << 16),
                 x1 - __uint_as_float(uh0 & 0xFFFF0000u));
    const unsigned uh1 = cvt2(x2, x3);
    hw[1] = uh1;
    lw[1] = cvt2(x2 - __uint_as_float(uh1 << 16),
                 x3 - __uint_as_float(uh1 & 0xFFFF0000u));
}

union BF8 { unsigned u[4]; bf16x8 v; };

// 8 packed words (hi<<16|lo) -> hi bf16x8 + lo bf16x8
__device__ __forceinline__ void unpack_pair(const unsigned* u, bf16x8& hi, bf16x8& lo) {
    BF8 h, l;
    #pragma unroll
    for (int p = 0; p < 4; ++p) {
        h.u[p] = (u[2 * p] >> 16)      | (u[2 * p + 1] & 0xFFFF0000u);
        l.u[p] = (u[2 * p] & 0xFFFFu)  | (u[2 * p + 1] << 16);
    }
    hi = h.v; lo = l.v;
}

// ============ weight pre-split: Wq/Wk/Wv -> hi/lo bf16 planes ============
__global__ __launch_bounds__(256)
void conv_w(const float* __restrict__ Wq, const float* __restrict__ Wk,
            const float* __restrict__ Wv,
            unsigned short* __restrict__ Wqh, unsigned short* __restrict__ Wql,
            unsigned short* __restrict__ Wkh, unsigned short* __restrict__ Wkl,
            unsigned short* __restrict__ Wvh, unsigned short* __restrict__ Wvl)
{
    const int NW8 = (D_MODEL * D_MODEL) / 8;      // 131072
    int i = blockIdx.x * 256 + threadIdx.x;
    const float* s; unsigned short *dh, *dl;
    if (i < NW8)            { s = Wq; dh = Wqh; dl = Wql; }
    else if (i < 2 * NW8)   { i -= NW8; s = Wk; dh = Wkh; dl = Wkl; }
    else                    { i -= 2 * NW8; s = Wv; dh = Wvh; dl = Wvl; }
    const float4 x0 = ((const float4*)(s + (size_t)i * 8))[0];
    const float4 x1 = ((const float4*)(s + (size_t)i * 8))[1];
    unsigned hw[4], lw[4];
    split4(x0.x, x0.y, x0.z, x0.w, &hw[0], &lw[0]);
    split4(x1.x, x1.y, x1.z, x1.w, &hw[2], &lw[2]);
    *(uint4*)&dh[(size_t)i * 8] = *(const uint4*)hw;
    *(uint4*)&dl[(size_t)i * 8] = *(const uint4*)lw;
}

// ============ fused Q/K/V projection (256 thr, 64x64/wave) ============
// z selects {Q,K,V}. A (input) split in-loop via cvt_pk; W pre-split planes.
// z<2: packed u32 (hi<<16|lo) head-split [B,H,S,dk], scaled (Q: 1/8).
// z==2: bf16 plane TRANSPOSED [B,H,dk,S] via LDS bounce, 256B-run stores.
// Grid (32,8,3): x=bm -> id%8 = bm%8 (A-row XCD locality).
__global__ __launch_bounds__(256, 3)
void proj_qkv(const float* __restrict__ q, const float* __restrict__ k,
              const float* __restrict__ v,
              const unsigned short* __restrict__ Wqh, const unsigned short* __restrict__ Wql,
              const unsigned short* __restrict__ Wkh, const unsigned short* __restrict__ Wkl,
              const unsigned short* __restrict__ Wvh, const unsigned short* __restrict__ Wvl,
              const float* __restrict__ bq, const float* __restrict__ bk,
              const float* __restrict__ bv,
              unsigned* __restrict__ qp, unsigned* __restrict__ kp,
              unsigned short* __restrict__ vt)
{
    __shared__ unsigned short SM[4][128][40];   // A_h, A_l, B_h, B_l
    unsigned short (*A_h)[40] = SM[0];
    unsigned short (*A_l)[40] = SM[1];
    unsigned short (*B_h)[40] = SM[2];
    unsigned short (*B_l)[40] = SM[3];

    const int z = blockIdx.z;
    const float* X    = (z == 0) ? q   : (z == 1) ? k   : v;
    const unsigned short* Wh = (z == 0) ? Wqh : (z == 1) ? Wkh : Wvh;
    const unsigned short* Wl = (z == 0) ? Wql : (z == 1) ? Wkl : Wvl;
    const float* bias = (z == 0) ? bq  : (z == 1) ? bk  : bv;
    const float scale = (z == 0) ? 0.125f : 1.0f;

    const int K = D_MODEL;
    const int tid = threadIdx.x, lane = tid & 63;
    const int l15 = lane & 15, l4 = lane >> 4;
    const int wv4 = tid >> 6;
    const int wr = (wv4 >> 1) * 64, wc = (wv4 & 1) * 64;
    const int bm = blockIdx.x * 128, bn = blockIdx.y * 128;   // x=bm (XCD locality)
    const int sr = tid >> 1, sh = (tid & 1) * 16;

    f32x4 acc[4][4];
    #pragma unroll
    for (int i = 0; i < 4; ++i)
        #pragma unroll
        for (int j = 0; j < 4; ++j) acc[i][j] = (f32x4){0.f, 0.f, 0.f, 0.f};

    const float* ga = X + (size_t)(bm + sr) * K + sh;
    const unsigned short* gbh = Wh + (size_t)(bn + sr) * K + sh;
    const unsigned short* gbl = Wl + (size_t)(bn + sr) * K + sh;

    float4 av[4];
    uint4 wbh0, wbh1, wbl0, wbl1;
    #pragma unroll
    for (int l = 0; l < 4; ++l) av[l] = *(const float4*)&ga[l * 4];
    wbh0 = *(const uint4*)&gbh[0]; wbh1 = *(const uint4*)&gbh[8];
    wbl0 = *(const uint4*)&gbl[0]; wbl1 = *(const uint4*)&gbl[8];

    #pragma unroll 1
    for (int k0 = 0; k0 < K; k0 += 32) {
        // split A (cvt_pk path: ~3 VALU/value; productive latency filler)
        unsigned ahw[8], alw[8];
        #pragma unroll
        for (int l = 0; l < 4; ++l)
            split4(av[l].x, av[l].y, av[l].z, av[l].w, &ahw[l * 2], &alw[l * 2]);

        __syncthreads();                 // prior frag reads done
        *(uint4*)&A_h[sr][sh]     = *(const uint4*)&ahw[0];
        *(uint4*)&A_h[sr][sh + 8] = *(const uint4*)&ahw[4];
        *(uint4*)&A_l[sr][sh]     = *(const uint4*)&alw[0];
        *(uint4*)&A_l[sr][sh + 8] = *(const uint4*)&alw[4];
        *(uint4*)&B_h[sr][sh]     = wbh0;
        *(uint4*)&B_h[sr][sh + 8] = wbh1;
        *(uint4*)&B_l[sr][sh]     = wbl0;
        *(uint4*)&B_l[sr][sh + 8] = wbl1;
        __syncthreads();                 // tiles ready

        if (k0 + 32 < K) {               // issue next-step loads under MFMA
            const int o = k0 + 32;
            #pragma unroll
            for (int l = 0; l < 4; ++l) av[l] = *(const float4*)&ga[o + l * 4];
            wbh0 = *(const uint4*)&gbh[o]; wbh1 = *(const uint4*)&gbh[o + 8];
            wbl0 = *(const uint4*)&gbl[o]; wbl1 = *(const uint4*)&gbl[o + 8];
        }

        bf16x8 ah[4], al4[4], bh4[4], bl4[4];
        #pragma unroll
        for (int i = 0; i < 4; ++i) {
            const int r = wr + i * 16 + l15;
            const int c = wc + i * 16 + l15;
            ah[i]  = *(const bf16x8*)&A_h[r][l4 * 8];
            al4[i] = *(const bf16x8*)&A_l[r][l4 * 8];
            bh4[i] = *(const bf16x8*)&B_h[c][l4 * 8];
            bl4[i] = *(const bf16x8*)&B_l[c][l4 * 8];
        }
        #pragma unroll
        for (int i = 0; i < 4; ++i)
            #pragma unroll
            for (int j = 0; j < 4; ++j) {
                acc[i][j] = __builtin_amdgcn_mfma_f32_16x16x32_bf16(ah[i],  bh4[j], acc[i][j], 0, 0, 0);
                acc[i][j] = __builtin_amdgcn_mfma_f32_16x16x32_bf16(ah[i],  bl4[j], acc[i][j], 0, 0, 0);
                acc[i][j] = __builtin_amdgcn_mfma_f32_16x16x32_bf16(al4[i], bh4[j], acc[i][j], 0, 0, 0);
            }
    }

    if (z == 2) {
        // V: transpose bounce -> vt[B,H,dk,S]; 256B-run coalesced stores
        unsigned short* T = &SM[0][0][0];            // [128][136]
        __syncthreads();
        #pragma unroll
        for (int i = 0; i < 4; ++i)
            #pragma unroll
            for (int j = 0; j < 4; ++j) {
                const int cl = wc + j * 16 + l15;
                const int sl = wr + i * 16 + l4 * 4;
                const float bi = bias[bn + cl];
                unsigned short h4[4];
                #pragma unroll
                for (int r = 0; r < 4; ++r)
                    h4[r] = f2bf_rne(acc[i][j][r] + bi);
                *(uint2*)&T[cl * 136 + sl] = *(const uint2*)&h4[0];
            }
        __syncthreads();
        const int c = tid >> 1, half = tid & 1;
        const int bb = bm >> 10;
        const int sb = (bm & (SEQ - 1)) + half * 64;
        unsigned short* dst = vt + (((size_t)bb << 20) + (size_t)(bn + c) * SEQ + sb);
        const unsigned short* srcT = &T[c * 136 + half * 64];
        #pragma unroll
        for (int u = 0; u < 8; ++u)
            *(uint4*)&dst[u * 8] = *(const uint4*)&srcT[u * 8];
        return;
    }

    // Q/K: packed u32, head-split
    unsigned* Cp = (z == 0) ? qp : kp;
    #pragma unroll
    for (int i = 0; i < 4; ++i)
        #pragma unroll
        for (int j = 0; j < 4; ++j) {
            const int rb = bm + wr + i * 16 + l4 * 4;
            const int c  = bn + wc + j * 16 + l15;
            const float bi = bias[c];
            const int h = c >> 6, d = c & (D_HEAD - 1);
            #pragma unroll
            for (int r = 0; r < 4; ++r) {
                const float val = (acc[i][j][r] + bi) * scale;
                const unsigned short hu = f2bf_rne(val);
                const unsigned short lu = f2bf_rne(val - bf2f(hu));
                const int mrow = rb + r;
                const int b = mrow >> 10, s = mrow & (SEQ - 1);
                Cp[((size_t)(b * N_HEADS + h) * SEQ + s) * D_HEAD + d] =
                    ((unsigned)hu << 16) | lu;
            }
        }
}

// ============ O projection: 64x128 tile, grid (64,8) = 2 blocks/CU ============
// bf16 ctx plane x hi(Wo) -> fp32 out. Wave = 32x64 (2x2 wave grid).
__global__ __launch_bounds__(256, 2)
void proj_o(const unsigned short* __restrict__ Act, const float* __restrict__ W,
            const float* __restrict__ bias, float* __restrict__ out)
{
    __shared__ unsigned short A_h[64][40];
    __shared__ unsigned short B_h[128][40];

    const int K = D_MODEL;
    const int tid = threadIdx.x, lane = tid & 63;
    const int l15 = lane & 15, l4 = lane >> 4;
    const int wv4 = tid >> 6;
    const int wr = (wv4 >> 1) * 32, wc = (wv4 & 1) * 64;
    const int bm = blockIdx.x * 64, bn = blockIdx.y * 128;   // x=bm (A XCD locality)
    const int sra = tid >> 2, sha = (tid & 3) * 8;   // A: 64x32 ushort, 8/thread
    const int srb = tid >> 1, shb = (tid & 1) * 16;  // B: 128x32 f32 -> bf16, 16/thread

    f32x4 acc[2][4];
    #pragma unroll
    for (int i = 0; i < 2; ++i)
        #pragma unroll
        for (int j = 0; j < 4; ++j) acc[i][j] = (f32x4){0.f, 0.f, 0.f, 0.f};

    const unsigned short* ga = Act + (size_t)(bm + sra) * K + sha;
    const float* gb = W + (size_t)(bn + srb) * K + shb;

    uint4 av0 = *(const uint4*)&ga[0];
    float4 bv4[4];
    #pragma unroll
    for (int l = 0; l < 4; ++l) bv4[l] = *(const float4*)&gb[l * 4];

    #pragma unroll 1
    for (int k0 = 0; k0 < K; k0 += 32) {
        unsigned bhw[8];
        #pragma unroll
        for (int l = 0; l < 4; ++l) {
            bhw[l * 2]     = cvt2(bv4[l].x, bv4[l].y);
            bhw[l * 2 + 1] = cvt2(bv4[l].z, bv4[l].w);
        }

        __syncthreads();
        *(uint4*)&A_h[sra][sha]   = av0;
        *(uint4*)&B_h[srb][shb]     = *(const uint4*)&bhw[0];
        *(uint4*)&B_h[srb][shb + 8] = *(const uint4*)&bhw[4];
        __syncthreads();

        if (k0 + 32 < K) {
            av0 = *(const uint4*)&ga[k0 + 32];
            #pragma unroll
            for (int l = 0; l < 4; ++l)
                bv4[l] = *(const float4*)&gb[k0 + 32 + l * 4];
        }

        bf16x8 ah[2], bh4[4];
        #pragma unroll
        for (int i = 0; i < 2; ++i)
            ah[i] = *(const bf16x8*)&A_h[wr + i * 16 + l15][l4 * 8];
        #pragma unroll
        for (int j = 0; j < 4; ++j)
            bh4[j] = *(const bf16x8*)&B_h[wc + j * 16 + l15][l4 * 8];
        #pragma unroll
        for (int i = 0; i < 2; ++i)
            #pragma unroll
            for (int j = 0; j < 4; ++j)
                acc[i][j] = __builtin_amdgcn_mfma_f32_16x16x32_bf16(ah[i], bh4[j], acc[i][j], 0, 0, 0);
    }

    #pragma unroll
    for (int i = 0; i < 2; ++i)
        #pragma unroll
        for (int j = 0; j < 4; ++j) {
            const int rb = bm + wr + i * 16 + l4 * 4;
            const int c  = bn + wc + j * 16 + l15;
            const float bi = bias[c];
            #pragma unroll
            for (int r = 0; r < 4; ++r)
                out[(size_t)(rb + r) * D_MODEL + c] = acc[i][j][r] + bi;
        }
}

// ============ MFMA attention (8 waves x 16q, 4 waves/SIMD) ============
__device__ __forceinline__ void score16(
    const unsigned short (* __restrict__ KH)[72], const unsigned short (* __restrict__ KL)[72],
    int l15, int l4, const bf16x8 (&qh)[2], const bf16x8 (&ql)[2], f32x4 acc[4])
{
    #pragma unroll
    for (int j = 0; j < 4; ++j) {
        const int row = l15 + 16 * j;
        const bf16x8 kh0 = *(const bf16x8*)&KH[row][l4 * 8];
        const bf16x8 kh1 = *(const bf16x8*)&KH[row][32 + l4 * 8];
        const bf16x8 kl0 = *(const bf16x8*)&KL[row][l4 * 8];
        const bf16x8 kl1 = *(const bf16x8*)&KL[row][32 + l4 * 8];
        f32x4 a = (f32x4){0.f, 0.f, 0.f, 0.f};
        a = __builtin_amdgcn_mfma_f32_16x16x32_bf16(qh[0], kh0, a, 0, 0, 0);
        a = __builtin_amdgcn_mfma_f32_16x16x32_bf16(qh[0], kl0, a, 0, 0, 0);
        a = __builtin_amdgcn_mfma_f32_16x16x32_bf16(ql[0], kh0, a, 0, 0, 0);
        a = __builtin_amdgcn_mfma_f32_16x16x32_bf16(qh[1], kh1, a, 0, 0, 0);
        a = __builtin_amdgcn_mfma_f32_16x16x32_bf16(qh[1], kl1, a, 0, 0, 0);
        a = __builtin_amdgcn_mfma_f32_16x16x32_bf16(ql[1], kh1, a, 0, 0, 0);
        acc[j] = a;
    }
}

__global__ __launch_bounds__(512, 4)
void attn_mfma(const unsigned* __restrict__ qp, const unsigned* __restrict__ kp,
               const unsigned short* __restrict__ vt, unsigned short* __restrict__ ctxh)
{
    __shared__ unsigned short KHL[2][2][64][72];   // 36864 B
    __shared__ unsigned short Wl[8][16][64];       // 16384 B, per-wave W [q][k]
    __shared__ float Vm[64];
    __shared__ int AnyNU;
    // Pm aliased into Wl: Pm dead after Vm (prologue barrier); Wl used in pass B.
    float (*Pm)[8] = (float (*)[8])&Wl[0][0][0];   // [64][8] f32 = 2KB

    const int tid  = threadIdx.x;
    const int lane = tid & 63;
    const int wv   = tid >> 6;                     // 0..7
    const int l15  = lane & 15, l4 = lane >> 4;
    const int bh   = blockIdx.x;                   // XCD locality: id%8 = bh%8
    const int b    = bh >> 4, h = bh & 15;
    const int q0   = blockIdx.y * 128 + wv * 16;   // 16 q per wave

    // ---- Q fragments (packed -> hi/lo), 16 rows ----
    bf16x8 qh[2], ql[2];
    {
        const unsigned* qrow = qp + ((size_t)bh * SEQ + q0 + l15) * D_HEAD;
        #pragma unroll
        for (int ks = 0; ks < 2; ++ks) {
            unsigned u[8];
            *(uint4*)&u[0] = *(const uint4*)&qrow[ks * 32 + l4 * 8];
            *(uint4*)&u[4] = *(const uint4*)&qrow[ks * 32 + l4 * 8 + 4];
            unpack_pair(u, qh[ks], ql[ks]);
        }
    }

    const unsigned short* vtb = vt + (size_t)bh * D_HEAD * SEQ;

    // ---- vmean partials: thread t sums 128 V values of row d = t>>3 ----
    {
        const int d = tid >> 3, q8 = tid & 7;
        const unsigned short* vr = vtb + (size_t)d * SEQ + q8 * 128;
        float s0 = 0.f, s1 = 0.f, s2 = 0.f, s3 = 0.f;
        #pragma unroll 4
        for (int i = 0; i < 16; ++i) {
            bf16x8 v8 = *(const bf16x8*)&vr[i * 8];
            s0 += bf2f((unsigned short)v8[0]) + bf2f((unsigned short)v8[4]);
            s1 += bf2f((unsigned short)v8[1]) + bf2f((unsigned short)v8[5]);
            s2 += bf2f((unsigned short)v8[2]) + bf2f((unsigned short)v8[6]);
            s3 += bf2f((unsigned short)v8[3]) + bf2f((unsigned short)v8[7]);
        }
        Pm[d][q8] = (s0 + s1) + (s2 + s3);
        if (tid == 0) AnyNU = 0;
    }

    // staging: 512 threads cover 64 k-rows x 64 words; sr = tid>>3, sd = (tid&7)*8
    const int sr = tid >> 3;
    const int sd = (tid & 7) * 8;
    const unsigned* kpb = kp + (size_t)bh * SEQ * D_HEAD;

    {   // prologue: stage chunk 0 -> buf 0
        unsigned u[8];
        const unsigned* src = kpb + (size_t)sr * D_HEAD + sd;
        *(uint4*)&u[0] = *(const uint4*)&src[0];
        *(uint4*)&u[4] = *(const uint4*)&src[4];
        bf16x8 h0, l0;
        unpack_pair(u, h0, l0);
        *(bf16x8*)&KHL[0][0][sr][sd] = h0;
        *(bf16x8*)&KHL[0][1][sr][sd] = l0;
    }
    __syncthreads();

    if (tid < 64)
        Vm[tid] = (((Pm[tid][0] + Pm[tid][1]) + (Pm[tid][2] + Pm[tid][3]))
                 + ((Pm[tid][4] + Pm[tid][5]) + (Pm[tid][6] + Pm[tid][7]))) * (1.f / 1024.f);

    float mloc[4], zloc[4];
    #pragma unroll
    for (int r = 0; r < 4; ++r) { mloc[r] = -1e30f; zloc[r] = 0.f; }

    int cur = 0;

    // ========== pass A: Z = sum(e^s), m = max(s) ==========
    #pragma unroll 1
    for (int c = 0; c < 16; ++c) {
        unsigned u[8];                              // stage next chunk (issue early)
        const int cn = (c + 1) & 15;
        const unsigned* src = kpb + ((size_t)cn * 64 + sr) * D_HEAD + sd;
        *(uint4*)&u[0] = *(const uint4*)&src[0];
        *(uint4*)&u[4] = *(const uint4*)&src[4];

        f32x4 acc[4];
        score16(KHL[cur][0], KHL[cur][1], l15, l4, qh, ql, acc);

        #pragma unroll
        for (int r = 0; r < 4; ++r) {
            const float a0 = acc[0][r], a1 = acc[1][r];
            const float a2 = acc[2][r], a3 = acc[3][r];
            mloc[r] = fmaxf(mloc[r], fmaxf(fmaxf(a0, a1), fmaxf(a2, a3)));
            zloc[r] += (__expf(a0) + __expf(a1)) + (__expf(a2) + __expf(a3));
        }

        bf16x8 h0, l0;                              // write staged chunk (late)
        unpack_pair(u, h0, l0);
        const int nxt = cur ^ 1;
        *(bf16x8*)&KHL[nxt][0][sr][sd] = h0;
        *(bf16x8*)&KHL[nxt][1][sr][sd] = l0;
        __syncthreads();
        cur = nxt;
    }

    // ---- merge over 16-lane col groups; tau test; uniform detect ----
    float taue[4];
    bool  unif[4];
    int mynu = 0;
    #pragma unroll
    for (int r = 0; r < 4; ++r) {
        float mm = mloc[r], zz = zloc[r];
        #pragma unroll
        for (int o = 1; o <= 8; o <<= 1) {
            mm = fmaxf(mm, __shfl_xor(mm, o, 16));
            zz += __shfl_xor(zz, o, 16);
        }
        const float tau = __logf(SPARSE_THRESH * zz);
        const bool uni = (mm < tau);
        unif[r] = uni;
        taue[r] = uni ? 3.0e38f : tau;
        mynu |= uni ? 0 : 1;
    }
    if (__any(mynu)) { if (lane == 0) atomicOr(&AnyNU, 1); }
    __syncthreads();
    const bool runB = (AnyNU != 0);

    float z2[4];
    f32x4 pv[4];
    #pragma unroll
    for (int r = 0; r < 4; ++r) { z2[r] = 0.f; pv[r] = (f32x4){0.f, 0.f, 0.f, 0.f}; }

    // ========== pass B: only if a non-uniform row exists ==========
    if (runB) {
        #pragma unroll 1
        for (int c = 0; c < 16; ++c) {
            unsigned u[8];
            const int cn = (c + 1) & 15;
            const unsigned* src = kpb + ((size_t)cn * 64 + sr) * D_HEAD + sd;
            *(uint4*)&u[0] = *(const uint4*)&src[0];
            *(uint4*)&u[4] = *(const uint4*)&src[4];

            f32x4 acc[4];
            score16(KHL[cur][0], KHL[cur][1], l15, l4, qh, ql, acc);   // bit-identical

            int any = 0;
            #pragma unroll
            for (int r = 0; r < 4; ++r) {
                const float rmax = fmaxf(fmaxf(acc[0][r], acc[1][r]),
                                         fmaxf(acc[2][r], acc[3][r]));
                any |= (rmax >= taue[r]) ? 1 : 0;
            }

            if (__any(any)) {
                #pragma unroll
                for (int j = 0; j < 4; ++j)
                    #pragma unroll
                    for (int r = 0; r < 4; ++r) {
                        const float a = acc[j][r];
                        const float w = (a >= taue[r]) ? __expf(a) : 0.f;
                        const unsigned short wb = f2bf_rne(w);
                        z2[r] += bf2f(wb);
                        Wl[wv][l4 * 4 + r][l15 + 16 * j] = wb;
                    }
                asm volatile("s_waitcnt lgkmcnt(0)" ::: "memory");
                __builtin_amdgcn_sched_barrier(0);

                bf16x8 wa[2];
                #pragma unroll
                for (int ks = 0; ks < 2; ++ks)
                    wa[ks] = *(const bf16x8*)&Wl[wv][l15][ks * 32 + l4 * 8];

                #pragma unroll
                for (int ds = 0; ds < 4; ++ds) {
                    const bf16x8 v0 = *(const bf16x8*)
                        &vtb[(size_t)(ds * 16 + l15) * SEQ + c * 64 + l4 * 8];
                    const bf16x8 v1 = *(const bf16x8*)
                        &vtb[(size_t)(ds * 16 + l15) * SEQ + c * 64 + 32 + l4 * 8];
                    pv[ds] = __builtin_amdgcn_mfma_f32_16x16x32_bf16(wa[0], v0, pv[ds], 0, 0, 0);
                    pv[ds] = __builtin_amdgcn_mfma_f32_16x16x32_bf16(wa[1], v1, pv[ds], 0, 0, 0);
                }
            }

            bf16x8 h0, l0;
            unpack_pair(u, h0, l0);
            const int nxt = cur ^ 1;
            *(bf16x8*)&KHL[nxt][0][sr][sd] = h0;
            *(bf16x8*)&KHL[nxt][1][sr][sd] = l0;
            __syncthreads();
            cur = nxt;
        }

        #pragma unroll
        for (int r = 0; r < 4; ++r) {
            #pragma unroll
            for (int o = 1; o <= 8; o <<= 1) z2[r] += __shfl_xor(z2[r], o, 16);
        }
    }

    // ---- epilogue: select vmean vs pv/z2; per-wave bounce [16][68] f32 ----
    float* Tw = (float*)&KHL[0][0][0][0] + wv * 1088;   // 16*68 = 1088 f32/wave
    #pragma unroll
    for (int r = 0; r < 4; ++r) {
        const float inv = unif[r] ? 0.f : (1.f / z2[r]);
        const int row = l4 * 4 + r;
        #pragma unroll
        for (int ds = 0; ds < 4; ++ds) {
            const int d = ds * 16 + l15;
            Tw[row * 68 + d] = unif[r] ? Vm[d] : pv[ds][r] * inv;
        }
    }
    asm volatile("s_waitcnt lgkmcnt(0)" ::: "memory");
    __builtin_amdgcn_sched_barrier(0);

    // lane -> row rr = lane>>2 (16 rows), seg = lane&3 (16 f32 each)
    const int rr = lane >> 2, seg = lane & 3;
    const size_t gbase = ((size_t)b * SEQ + q0 + rr) * D_MODEL + h * D_HEAD + seg * 16;
    #pragma unroll
    for (int u2 = 0; u2 < 4; ++u2) {
        const float4 t = *(const float4*)&Tw[rr * 68 + seg * 16 + u2 * 4];
        unsigned short h4[4] = {f2bf_rne(t.x), f2bf_rne(t.y), f2bf_rne(t.z), f2bf_rne(t.w)};
        *(uint2*)&ctxh[gbase + u2 * 4] = *(const uint2*)h4;
    }
}

extern "C" void kernel_launch(void* const* d_in, const int* in_sizes, int n_in,
                              void* d_out, int out_size, void* d_ws, size_t ws_size,
                              hipStream_t stream)
{
    const float* q  = (const float*)d_in[0];
    const float* k  = (const float*)d_in[1];
    const float* v  = (const float*)d_in[2];
    const float* Wq = (const float*)d_in[3];
    const float* bq = (const float*)d_in[4];
    const float* Wk = (const float*)d_in[5];
    const float* bk = (const float*)d_in[6];
    const float* Wv = (const float*)d_in[7];
    const float* bv = (const float*)d_in[8];
    const float* Wo = (const float*)d_in[9];
    const float* bo = (const float*)d_in[10];
    float* out = (float*)d_out;

    // workspace (60 MiB): qp 16 + kp 16 + vt 8 + ctxh 8 + 6 weight planes (12)
    const size_t MB = 1 << 20;
    char* w = (char*)d_ws;
    unsigned* qp = (unsigned*)(w);
    unsigned* kp = (unsigned*)(w + 16 * MB);
    unsigned short* vt   = (unsigned short*)(w + 32 * MB);
    unsigned short* ctxh = (unsigned short*)(w + 40 * MB);
    unsigned short* Wqh = (unsigned short*)(w + 48 * MB);
    unsigned short* Wql = (unsigned short*)(w + 50 * MB);
    unsigned short* Wkh = (unsigned short*)(w + 52 * MB);
    unsigned short* Wkl = (unsigned short*)(w + 54 * MB);
    unsigned short* Wvh = (unsigned short*)(w + 56 * MB);
    unsigned short* Wvl = (unsigned short*)(w + 58 * MB);

    const int NW8 = (D_MODEL * D_MODEL) / 8;      // 131072

    // pre-split the 3 weight matrices (removes 32x-redundant in-loop W conversion)
    conv_w<<<(3 * NW8) / 256, 256, 0, stream>>>(Wq, Wk, Wv, Wqh, Wql, Wkh, Wkl, Wvh, Wvl);

    // fused Q/K/V: grid (32,8,3), x=bm -> id%8 = bm%8 (A-row XCD locality)
    proj_qkv<<<dim3(32, 8, 3), 256, 0, stream>>>(q, k, v,
                                                 Wqh, Wql, Wkh, Wkl, Wvh, Wvl,
                                                 bq, bk, bv, qp, kp, vt);

    // bh on x: all 8 q-blocks of a (b,h) share an XCD (id%8 = bh%8)
    attn_mfma<<<dim3(BATCH * N_HEADS, SEQ / 128), 512, 0, stream>>>(qp, kp, vt, ctxh);

    // O: 64x128 tiles, (64,8) = 512 blocks = 2/CU (was 1/CU stall regime)
    proj_o<<<dim3(64, 8), 256, 0, stream>>>(ctxh, Wo, bo, out);
}

// Round 22
// 168.948 us; speedup vs baseline: 1.0846x; 1.0252x over previous
//
#include <hip/hip_runtime.h>
#include <hip/hip_bf16.h>
#include <math.h>

// Sparse MHA encoder: B=4, S=1024, D=1024, H=16, dk=64.
// Numerics: the 0.09 threshold is a step function on first-pass softmax.
// Score path (Q/K projections + QK^T) is split-bf16 (hi+lo, ~2^-18 rel err)
// -> E[mask flips] ~1e-4. Post-mask paths (PV, ctx, O-proj) direct bf16.
// Pass B recomputes scores BIT-IDENTICALLY to pass A (same helper, same LDS).
// Uniform-row skip: row all-masked <=> rowmax < tau = log(0.09*Z).
// R22: (a) attn score16: 6-deep MFMA chain -> two independent 3-chains +
// f32x4 add (halves chain-latency on the chunk critical path; reassociation
// ~1e-7 rel, pass A/B still share the helper -> consistent); (b) proj_o ->
// 64x64 tiles, grid (64,16) = 1024 blocks = 4/CU (residency ladder cont.).

constexpr int D_MODEL = 1024;
constexpr int N_HEADS = 16;
constexpr int D_HEAD  = 64;
constexpr int SEQ     = 1024;
constexpr int BATCH   = 4;
constexpr float SPARSE_THRESH = 0.09f;

typedef short  bf16x8 __attribute__((ext_vector_type(8)));
typedef float  f32x4  __attribute__((ext_vector_type(4)));

__device__ __forceinline__ unsigned short f2bf_rne(float x) {
    unsigned u = __float_as_uint(x);
    u += 0x7FFFu + ((u >> 16) & 1u);          // round-to-nearest-even
    return (unsigned short)(u >> 16);
}
__device__ __forceinline__ float bf2f(unsigned short b) {
    return __uint_as_float(((unsigned)b) << 16);
}

// packed RNE pair-convert: low16 = bf16(a), high16 = bf16(b)  (v_cvt_pk_bf16_f32)
__device__ __forceinline__ unsigned cvt2(float a, float b) {
    __hip_bfloat162 p = __float22bfloat162_rn(make_float2(a, b));
    unsigned u; __builtin_memcpy(&u, &p, 4); return u;
}
// split 4 floats -> 2 packed hi words + 2 packed lo words
__device__ __forceinline__ void split4(float x0, float x1, float x2, float x3,
                                       unsigned* hw, unsigned* lw) {
    const unsigned uh0 = cvt2(x0, x1);
    hw[0] = uh0;
    lw[0] = cvt2(x0 - __uint_as_float(uh0 << 16),
                 x1 - __uint_as_float(uh0 & 0xFFFF0000u));
    const unsigned uh1 = cvt2(x2, x3);
    hw[1] = uh1;
    lw[1] = cvt2(x2 - __uint_as_float(uh1 << 16),
                 x3 - __uint_as_float(uh1 & 0xFFFF0000u));
}

union BF8 { unsigned u[4]; bf16x8 v; };

// 8 packed words (hi<<16|lo) -> hi bf16x8 + lo bf16x8
__device__ __forceinline__ void unpack_pair(const unsigned* u, bf16x8& hi, bf16x8& lo) {
    BF8 h, l;
    #pragma unroll
    for (int p = 0; p < 4; ++p) {
        h.u[p] = (u[2 * p] >> 16)      | (u[2 * p + 1] & 0xFFFF0000u);
        l.u[p] = (u[2 * p] & 0xFFFFu)  | (u[2 * p + 1] << 16);
    }
    hi = h.v; lo = l.v;
}

// ============ weight pre-split: Wq/Wk/Wv -> hi/lo bf16 planes ============
__global__ __launch_bounds__(256)
void conv_w(const float* __restrict__ Wq, const float* __restrict__ Wk,
            const float* __restrict__ Wv,
            unsigned short* __restrict__ Wqh, unsigned short* __restrict__ Wql,
            unsigned short* __restrict__ Wkh, unsigned short* __restrict__ Wkl,
            unsigned short* __restrict__ Wvh, unsigned short* __restrict__ Wvl)
{
    const int NW8 = (D_MODEL * D_MODEL) / 8;      // 131072
    int i = blockIdx.x * 256 + threadIdx.x;
    const float* s; unsigned short *dh, *dl;
    if (i < NW8)            { s = Wq; dh = Wqh; dl = Wql; }
    else if (i < 2 * NW8)   { i -= NW8; s = Wk; dh = Wkh; dl = Wkl; }
    else                    { i -= 2 * NW8; s = Wv; dh = Wvh; dl = Wvl; }
    const float4 x0 = ((const float4*)(s + (size_t)i * 8))[0];
    const float4 x1 = ((const float4*)(s + (size_t)i * 8))[1];
    unsigned hw[4], lw[4];
    split4(x0.x, x0.y, x0.z, x0.w, &hw[0], &lw[0]);
    split4(x1.x, x1.y, x1.z, x1.w, &hw[2], &lw[2]);
    *(uint4*)&dh[(size_t)i * 8] = *(const uint4*)hw;
    *(uint4*)&dl[(size_t)i * 8] = *(const uint4*)lw;
}

// ============ fused Q/K/V projection (256 thr, 64x64/wave) ============
// z selects {Q,K,V}. A (input) split in-loop via cvt_pk; W pre-split planes.
// z<2: packed u32 (hi<<16|lo) head-split [B,H,S,dk], scaled (Q: 1/8).
// z==2: bf16 plane TRANSPOSED [B,H,dk,S] via LDS bounce, 256B-run stores.
// Grid (32,8,3): x=bm -> id%8 = bm%8 (A-row XCD locality).
__global__ __launch_bounds__(256, 3)
void proj_qkv(const float* __restrict__ q, const float* __restrict__ k,
              const float* __restrict__ v,
              const unsigned short* __restrict__ Wqh, const unsigned short* __restrict__ Wql,
              const unsigned short* __restrict__ Wkh, const unsigned short* __restrict__ Wkl,
              const unsigned short* __restrict__ Wvh, const unsigned short* __restrict__ Wvl,
              const float* __restrict__ bq, const float* __restrict__ bk,
              const float* __restrict__ bv,
              unsigned* __restrict__ qp, unsigned* __restrict__ kp,
              unsigned short* __restrict__ vt)
{
    __shared__ unsigned short SM[4][128][40];   // A_h, A_l, B_h, B_l
    unsigned short (*A_h)[40] = SM[0];
    unsigned short (*A_l)[40] = SM[1];
    unsigned short (*B_h)[40] = SM[2];
    unsigned short (*B_l)[40] = SM[3];

    const int z = blockIdx.z;
    const float* X    = (z == 0) ? q   : (z == 1) ? k   : v;
    const unsigned short* Wh = (z == 0) ? Wqh : (z == 1) ? Wkh : Wvh;
    const unsigned short* Wl = (z == 0) ? Wql : (z == 1) ? Wkl : Wvl;
    const float* bias = (z == 0) ? bq  : (z == 1) ? bk  : bv;
    const float scale = (z == 0) ? 0.125f : 1.0f;

    const int K = D_MODEL;
    const int tid = threadIdx.x, lane = tid & 63;
    const int l15 = lane & 15, l4 = lane >> 4;
    const int wv4 = tid >> 6;
    const int wr = (wv4 >> 1) * 64, wc = (wv4 & 1) * 64;
    const int bm = blockIdx.x * 128, bn = blockIdx.y * 128;   // x=bm (XCD locality)
    const int sr = tid >> 1, sh = (tid & 1) * 16;

    f32x4 acc[4][4];
    #pragma unroll
    for (int i = 0; i < 4; ++i)
        #pragma unroll
        for (int j = 0; j < 4; ++j) acc[i][j] = (f32x4){0.f, 0.f, 0.f, 0.f};

    const float* ga = X + (size_t)(bm + sr) * K + sh;
    const unsigned short* gbh = Wh + (size_t)(bn + sr) * K + sh;
    const unsigned short* gbl = Wl + (size_t)(bn + sr) * K + sh;

    float4 av[4];
    uint4 wbh0, wbh1, wbl0, wbl1;
    #pragma unroll
    for (int l = 0; l < 4; ++l) av[l] = *(const float4*)&ga[l * 4];
    wbh0 = *(const uint4*)&gbh[0]; wbh1 = *(const uint4*)&gbh[8];
    wbl0 = *(const uint4*)&gbl[0]; wbl1 = *(const uint4*)&gbl[8];

    #pragma unroll 1
    for (int k0 = 0; k0 < K; k0 += 32) {
        // split A (cvt_pk path: ~3 VALU/value; productive latency filler)
        unsigned ahw[8], alw[8];
        #pragma unroll
        for (int l = 0; l < 4; ++l)
            split4(av[l].x, av[l].y, av[l].z, av[l].w, &ahw[l * 2], &alw[l * 2]);

        __syncthreads();                 // prior frag reads done
        *(uint4*)&A_h[sr][sh]     = *(const uint4*)&ahw[0];
        *(uint4*)&A_h[sr][sh + 8] = *(const uint4*)&ahw[4];
        *(uint4*)&A_l[sr][sh]     = *(const uint4*)&alw[0];
        *(uint4*)&A_l[sr][sh + 8] = *(const uint4*)&alw[4];
        *(uint4*)&B_h[sr][sh]     = wbh0;
        *(uint4*)&B_h[sr][sh + 8] = wbh1;
        *(uint4*)&B_l[sr][sh]     = wbl0;
        *(uint4*)&B_l[sr][sh + 8] = wbl1;
        __syncthreads();                 // tiles ready

        if (k0 + 32 < K) {               // issue next-step loads under MFMA
            const int o = k0 + 32;
            #pragma unroll
            for (int l = 0; l < 4; ++l) av[l] = *(const float4*)&ga[o + l * 4];
            wbh0 = *(const uint4*)&gbh[o]; wbh1 = *(const uint4*)&gbh[o + 8];
            wbl0 = *(const uint4*)&gbl[o]; wbl1 = *(const uint4*)&gbl[o + 8];
        }

        bf16x8 ah[4], al4[4], bh4[4], bl4[4];
        #pragma unroll
        for (int i = 0; i < 4; ++i) {
            const int r = wr + i * 16 + l15;
            const int c = wc + i * 16 + l15;
            ah[i]  = *(const bf16x8*)&A_h[r][l4 * 8];
            al4[i] = *(const bf16x8*)&A_l[r][l4 * 8];
            bh4[i] = *(const bf16x8*)&B_h[c][l4 * 8];
            bl4[i] = *(const bf16x8*)&B_l[c][l4 * 8];
        }
        #pragma unroll
        for (int i = 0; i < 4; ++i)
            #pragma unroll
            for (int j = 0; j < 4; ++j) {
                acc[i][j] = __builtin_amdgcn_mfma_f32_16x16x32_bf16(ah[i],  bh4[j], acc[i][j], 0, 0, 0);
                acc[i][j] = __builtin_amdgcn_mfma_f32_16x16x32_bf16(ah[i],  bl4[j], acc[i][j], 0, 0, 0);
                acc[i][j] = __builtin_amdgcn_mfma_f32_16x16x32_bf16(al4[i], bh4[j], acc[i][j], 0, 0, 0);
            }
    }

    if (z == 2) {
        // V: transpose bounce -> vt[B,H,dk,S]; 256B-run coalesced stores
        unsigned short* T = &SM[0][0][0];            // [128][136]
        __syncthreads();
        #pragma unroll
        for (int i = 0; i < 4; ++i)
            #pragma unroll
            for (int j = 0; j < 4; ++j) {
                const int cl = wc + j * 16 + l15;
                const int sl = wr + i * 16 + l4 * 4;
                const float bi = bias[bn + cl];
                unsigned short h4[4];
                #pragma unroll
                for (int r = 0; r < 4; ++r)
                    h4[r] = f2bf_rne(acc[i][j][r] + bi);
                *(uint2*)&T[cl * 136 + sl] = *(const uint2*)&h4[0];
            }
        __syncthreads();
        const int c = tid >> 1, half = tid & 1;
        const int bb = bm >> 10;
        const int sb = (bm & (SEQ - 1)) + half * 64;
        unsigned short* dst = vt + (((size_t)bb << 20) + (size_t)(bn + c) * SEQ + sb);
        const unsigned short* srcT = &T[c * 136 + half * 64];
        #pragma unroll
        for (int u = 0; u < 8; ++u)
            *(uint4*)&dst[u * 8] = *(const uint4*)&srcT[u * 8];
        return;
    }

    // Q/K: packed u32, head-split
    unsigned* Cp = (z == 0) ? qp : kp;
    #pragma unroll
    for (int i = 0; i < 4; ++i)
        #pragma unroll
        for (int j = 0; j < 4; ++j) {
            const int rb = bm + wr + i * 16 + l4 * 4;
            const int c  = bn + wc + j * 16 + l15;
            const float bi = bias[c];
            const int h = c >> 6, d = c & (D_HEAD - 1);
            #pragma unroll
            for (int r = 0; r < 4; ++r) {
                const float val = (acc[i][j][r] + bi) * scale;
                const unsigned short hu = f2bf_rne(val);
                const unsigned short lu = f2bf_rne(val - bf2f(hu));
                const int mrow = rb + r;
                const int b = mrow >> 10, s = mrow & (SEQ - 1);
                Cp[((size_t)(b * N_HEADS + h) * SEQ + s) * D_HEAD + d] =
                    ((unsigned)hu << 16) | lu;
            }
        }
}

// ============ O projection: 64x64 tile, grid (64,16) = 4 blocks/CU ============
// bf16 ctx plane x hi(Wo) -> fp32 out. Wave = 32x32 (2x2 wave grid).
__global__ __launch_bounds__(256, 4)
void proj_o(const unsigned short* __restrict__ Act, const float* __restrict__ W,
            const float* __restrict__ bias, float* __restrict__ out)
{
    __shared__ unsigned short A_h[64][40];
    __shared__ unsigned short B_h[64][40];

    const int K = D_MODEL;
    const int tid = threadIdx.x, lane = tid & 63;
    const int l15 = lane & 15, l4 = lane >> 4;
    const int wv4 = tid >> 6;
    const int wr = (wv4 >> 1) * 32, wc = (wv4 & 1) * 32;
    const int bm = blockIdx.x * 64, bn = blockIdx.y * 64;    // x=bm (A XCD locality)
    const int srt = tid >> 2, sht = (tid & 3) * 8;   // 64x32: 8 elems/thread

    f32x4 acc[2][2];
    #pragma unroll
    for (int i = 0; i < 2; ++i)
        #pragma unroll
        for (int j = 0; j < 2; ++j) acc[i][j] = (f32x4){0.f, 0.f, 0.f, 0.f};

    const unsigned short* ga = Act + (size_t)(bm + srt) * K + sht;
    const float* gb = W + (size_t)(bn + srt) * K + sht;

    uint4 av0 = *(const uint4*)&ga[0];
    float4 bv4[2];
    bv4[0] = *(const float4*)&gb[0];
    bv4[1] = *(const float4*)&gb[4];

    #pragma unroll 1
    for (int k0 = 0; k0 < K; k0 += 32) {
        unsigned bhw[4];
        bhw[0] = cvt2(bv4[0].x, bv4[0].y);
        bhw[1] = cvt2(bv4[0].z, bv4[0].w);
        bhw[2] = cvt2(bv4[1].x, bv4[1].y);
        bhw[3] = cvt2(bv4[1].z, bv4[1].w);

        __syncthreads();
        *(uint4*)&A_h[srt][sht] = av0;
        *(uint4*)&B_h[srt][sht] = *(const uint4*)&bhw[0];
        __syncthreads();

        if (k0 + 32 < K) {
            av0 = *(const uint4*)&ga[k0 + 32];
            bv4[0] = *(const float4*)&gb[k0 + 32];
            bv4[1] = *(const float4*)&gb[k0 + 32 + 4];
        }

        bf16x8 ah[2], bh4[2];
        #pragma unroll
        for (int i = 0; i < 2; ++i) {
            ah[i]  = *(const bf16x8*)&A_h[wr + i * 16 + l15][l4 * 8];
            bh4[i] = *(const bf16x8*)&B_h[wc + i * 16 + l15][l4 * 8];
        }
        #pragma unroll
        for (int i = 0; i < 2; ++i)
            #pragma unroll
            for (int j = 0; j < 2; ++j)
                acc[i][j] = __builtin_amdgcn_mfma_f32_16x16x32_bf16(ah[i], bh4[j], acc[i][j], 0, 0, 0);
    }

    #pragma unroll
    for (int i = 0; i < 2; ++i)
        #pragma unroll
        for (int j = 0; j < 2; ++j) {
            const int rb = bm + wr + i * 16 + l4 * 4;
            const int c  = bn + wc + j * 16 + l15;
            const float bi = bias[c];
            #pragma unroll
            for (int r = 0; r < 4; ++r)
                out[(size_t)(rb + r) * D_MODEL + c] = acc[i][j][r] + bi;
        }
}

// ============ MFMA attention (8 waves x 16q, 4 waves/SIMD) ============
// Two independent 3-deep MFMA chains (ks=0 / ks=1) + f32x4 add: halves the
// per-cell chain latency. Same helper in both passes -> consistent decisions.
__device__ __forceinline__ void score16(
    const unsigned short (* __restrict__ KH)[72], const unsigned short (* __restrict__ KL)[72],
    int l15, int l4, const bf16x8 (&qh)[2], const bf16x8 (&ql)[2], f32x4 acc[4])
{
    #pragma unroll
    for (int j = 0; j < 4; ++j) {
        const int row = l15 + 16 * j;
        const bf16x8 kh0 = *(const bf16x8*)&KH[row][l4 * 8];
        const bf16x8 kh1 = *(const bf16x8*)&KH[row][32 + l4 * 8];
        const bf16x8 kl0 = *(const bf16x8*)&KL[row][l4 * 8];
        const bf16x8 kl1 = *(const bf16x8*)&KL[row][32 + l4 * 8];
        f32x4 a0 = (f32x4){0.f, 0.f, 0.f, 0.f};
        f32x4 a1 = (f32x4){0.f, 0.f, 0.f, 0.f};
        a0 = __builtin_amdgcn_mfma_f32_16x16x32_bf16(qh[0], kh0, a0, 0, 0, 0);
        a1 = __builtin_amdgcn_mfma_f32_16x16x32_bf16(qh[1], kh1, a1, 0, 0, 0);
        a0 = __builtin_amdgcn_mfma_f32_16x16x32_bf16(qh[0], kl0, a0, 0, 0, 0);
        a1 = __builtin_amdgcn_mfma_f32_16x16x32_bf16(qh[1], kl1, a1, 0, 0, 0);
        a0 = __builtin_amdgcn_mfma_f32_16x16x32_bf16(ql[0], kh0, a0, 0, 0, 0);
        a1 = __builtin_amdgcn_mfma_f32_16x16x32_bf16(ql[1], kh1, a1, 0, 0, 0);
        acc[j] = a0 + a1;
    }
}

__global__ __launch_bounds__(512, 4)
void attn_mfma(const unsigned* __restrict__ qp, const unsigned* __restrict__ kp,
               const unsigned short* __restrict__ vt, unsigned short* __restrict__ ctxh)
{
    __shared__ unsigned short KHL[2][2][64][72];   // 36864 B
    __shared__ unsigned short Wl[8][16][64];       // 16384 B, per-wave W [q][k]
    __shared__ float Vm[64];
    __shared__ int AnyNU;
    // Pm aliased into Wl: Pm dead after Vm (prologue barrier); Wl used in pass B.
    float (*Pm)[8] = (float (*)[8])&Wl[0][0][0];   // [64][8] f32 = 2KB

    const int tid  = threadIdx.x;
    const int lane = tid & 63;
    const int wv   = tid >> 6;                     // 0..7
    const int l15  = lane & 15, l4 = lane >> 4;
    const int bh   = blockIdx.x;                   // XCD locality: id%8 = bh%8
    const int b    = bh >> 4, h = bh & 15;
    const int q0   = blockIdx.y * 128 + wv * 16;   // 16 q per wave

    // ---- Q fragments (packed -> hi/lo), 16 rows ----
    bf16x8 qh[2], ql[2];
    {
        const unsigned* qrow = qp + ((size_t)bh * SEQ + q0 + l15) * D_HEAD;
        #pragma unroll
        for (int ks = 0; ks < 2; ++ks) {
            unsigned u[8];
            *(uint4*)&u[0] = *(const uint4*)&qrow[ks * 32 + l4 * 8];
            *(uint4*)&u[4] = *(const uint4*)&qrow[ks * 32 + l4 * 8 + 4];
            unpack_pair(u, qh[ks], ql[ks]);
        }
    }

    const unsigned short* vtb = vt + (size_t)bh * D_HEAD * SEQ;

    // ---- vmean partials: thread t sums 128 V values of row d = t>>3 ----
    {
        const int d = tid >> 3, q8 = tid & 7;
        const unsigned short* vr = vtb + (size_t)d * SEQ + q8 * 128;
        float s0 = 0.f, s1 = 0.f, s2 = 0.f, s3 = 0.f;
        #pragma unroll 4
        for (int i = 0; i < 16; ++i) {
            bf16x8 v8 = *(const bf16x8*)&vr[i * 8];
            s0 += bf2f((unsigned short)v8[0]) + bf2f((unsigned short)v8[4]);
            s1 += bf2f((unsigned short)v8[1]) + bf2f((unsigned short)v8[5]);
            s2 += bf2f((unsigned short)v8[2]) + bf2f((unsigned short)v8[6]);
            s3 += bf2f((unsigned short)v8[3]) + bf2f((unsigned short)v8[7]);
        }
        Pm[d][q8] = (s0 + s1) + (s2 + s3);
        if (tid == 0) AnyNU = 0;
    }

    // staging: 512 threads cover 64 k-rows x 64 words; sr = tid>>3, sd = (tid&7)*8
    const int sr = tid >> 3;
    const int sd = (tid & 7) * 8;
    const unsigned* kpb = kp + (size_t)bh * SEQ * D_HEAD;

    {   // prologue: stage chunk 0 -> buf 0
        unsigned u[8];
        const unsigned* src = kpb + (size_t)sr * D_HEAD + sd;
        *(uint4*)&u[0] = *(const uint4*)&src[0];
        *(uint4*)&u[4] = *(const uint4*)&src[4];
        bf16x8 h0, l0;
        unpack_pair(u, h0, l0);
        *(bf16x8*)&KHL[0][0][sr][sd] = h0;
        *(bf16x8*)&KHL[0][1][sr][sd] = l0;
    }
    __syncthreads();

    if (tid < 64)
        Vm[tid] = (((Pm[tid][0] + Pm[tid][1]) + (Pm[tid][2] + Pm[tid][3]))
                 + ((Pm[tid][4] + Pm[tid][5]) + (Pm[tid][6] + Pm[tid][7]))) * (1.f / 1024.f);

    float mloc[4], zloc[4];
    #pragma unroll
    for (int r = 0; r < 4; ++r) { mloc[r] = -1e30f; zloc[r] = 0.f; }

    int cur = 0;

    // ========== pass A: Z = sum(e^s), m = max(s) ==========
    #pragma unroll 1
    for (int c = 0; c < 16; ++c) {
        unsigned u[8];                              // stage next chunk (issue early)
        const int cn = (c + 1) & 15;
        const unsigned* src = kpb + ((size_t)cn * 64 + sr) * D_HEAD + sd;
        *(uint4*)&u[0] = *(const uint4*)&src[0];
        *(uint4*)&u[4] = *(const uint4*)&src[4];

        f32x4 acc[4];
        score16(KHL[cur][0], KHL[cur][1], l15, l4, qh, ql, acc);

        #pragma unroll
        for (int r = 0; r < 4; ++r) {
            const float a0 = acc[0][r], a1 = acc[1][r];
            const float a2 = acc[2][r], a3 = acc[3][r];
            mloc[r] = fmaxf(mloc[r], fmaxf(fmaxf(a0, a1), fmaxf(a2, a3)));
            zloc[r] += (__expf(a0) + __expf(a1)) + (__expf(a2) + __expf(a3));
        }

        bf16x8 h0, l0;                              // write staged chunk (late)
        unpack_pair(u, h0, l0);
        const int nxt = cur ^ 1;
        *(bf16x8*)&KHL[nxt][0][sr][sd] = h0;
        *(bf16x8*)&KHL[nxt][1][sr][sd] = l0;
        __syncthreads();
        cur = nxt;
    }

    // ---- merge over 16-lane col groups; tau test; uniform detect ----
    float taue[4];
    bool  unif[4];
    int mynu = 0;
    #pragma unroll
    for (int r = 0; r < 4; ++r) {
        float mm = mloc[r], zz = zloc[r];
        #pragma unroll
        for (int o = 1; o <= 8; o <<= 1) {
            mm = fmaxf(mm, __shfl_xor(mm, o, 16));
            zz += __shfl_xor(zz, o, 16);
        }
        const float tau = __logf(SPARSE_THRESH * zz);
        const bool uni = (mm < tau);
        unif[r] = uni;
        taue[r] = uni ? 3.0e38f : tau;
        mynu |= uni ? 0 : 1;
    }
    if (__any(mynu)) { if (lane == 0) atomicOr(&AnyNU, 1); }
    __syncthreads();
    const bool runB = (AnyNU != 0);

    float z2[4];
    f32x4 pv[4];
    #pragma unroll
    for (int r = 0; r < 4; ++r) { z2[r] = 0.f; pv[r] = (f32x4){0.f, 0.f, 0.f, 0.f}; }

    // ========== pass B: only if a non-uniform row exists ==========
    if (runB) {
        #pragma unroll 1
        for (int c = 0; c < 16; ++c) {
            unsigned u[8];
            const int cn = (c + 1) & 15;
            const unsigned* src = kpb + ((size_t)cn * 64 + sr) * D_HEAD + sd;
            *(uint4*)&u[0] = *(const uint4*)&src[0];
            *(uint4*)&u[4] = *(const uint4*)&src[4];

            f32x4 acc[4];
            score16(KHL[cur][0], KHL[cur][1], l15, l4, qh, ql, acc);   // bit-identical

            int any = 0;
            #pragma unroll
            for (int r = 0; r < 4; ++r) {
                const float rmax = fmaxf(fmaxf(acc[0][r], acc[1][r]),
                                         fmaxf(acc[2][r], acc[3][r]));
                any |= (rmax >= taue[r]) ? 1 : 0;
            }

            if (__any(any)) {
                #pragma unroll
                for (int j = 0; j < 4; ++j)
                    #pragma unroll
                    for (int r = 0; r < 4; ++r) {
                        const float a = acc[j][r];
                        const float w = (a >= taue[r]) ? __expf(a) : 0.f;
                        const unsigned short wb = f2bf_rne(w);
                        z2[r] += bf2f(wb);
                        Wl[wv][l4 * 4 + r][l15 + 16 * j] = wb;
                    }
                asm volatile("s_waitcnt lgkmcnt(0)" ::: "memory");
                __builtin_amdgcn_sched_barrier(0);

                bf16x8 wa[2];
                #pragma unroll
                for (int ks = 0; ks < 2; ++ks)
                    wa[ks] = *(const bf16x8*)&Wl[wv][l15][ks * 32 + l4 * 8];

                #pragma unroll
                for (int ds = 0; ds < 4; ++ds) {
                    const bf16x8 v0 = *(const bf16x8*)
                        &vtb[(size_t)(ds * 16 + l15) * SEQ + c * 64 + l4 * 8];
                    const bf16x8 v1 = *(const bf16x8*)
                        &vtb[(size_t)(ds * 16 + l15) * SEQ + c * 64 + 32 + l4 * 8];
                    pv[ds] = __builtin_amdgcn_mfma_f32_16x16x32_bf16(wa[0], v0, pv[ds], 0, 0, 0);
                    pv[ds] = __builtin_amdgcn_mfma_f32_16x16x32_bf16(wa[1], v1, pv[ds], 0, 0, 0);
                }
            }

            bf16x8 h0, l0;
            unpack_pair(u, h0, l0);
            const int nxt = cur ^ 1;
            *(bf16x8*)&KHL[nxt][0][sr][sd] = h0;
            *(bf16x8*)&KHL[nxt][1][sr][sd] = l0;
            __syncthreads();
            cur = nxt;
        }

        #pragma unroll
        for (int r = 0; r < 4; ++r) {
            #pragma unroll
            for (int o = 1; o <= 8; o <<= 1) z2[r] += __shfl_xor(z2[r], o, 16);
        }
    }

    // ---- epilogue: select vmean vs pv/z2; per-wave bounce [16][68] f32 ----
    float* Tw = (float*)&KHL[0][0][0][0] + wv * 1088;   // 16*68 = 1088 f32/wave
    #pragma unroll
    for (int r = 0; r < 4; ++r) {
        const float inv = unif[r] ? 0.f : (1.f / z2[r]);
        const int row = l4 * 4 + r;
        #pragma unroll
        for (int ds = 0; ds < 4; ++ds) {
            const int d = ds * 16 + l15;
            Tw[row * 68 + d] = unif[r] ? Vm[d] : pv[ds][r] * inv;
        }
    }
    asm volatile("s_waitcnt lgkmcnt(0)" ::: "memory");
    __builtin_amdgcn_sched_barrier(0);

    // lane -> row rr = lane>>2 (16 rows), seg = lane&3 (16 f32 each)
    const int rr = lane >> 2, seg = lane & 3;
    const size_t gbase = ((size_t)b * SEQ + q0 + rr) * D_MODEL + h * D_HEAD + seg * 16;
    #pragma unroll
    for (int u2 = 0; u2 < 4; ++u2) {
        const float4 t = *(const float4*)&Tw[rr * 68 + seg * 16 + u2 * 4];
        unsigned short h4[4] = {f2bf_rne(t.x), f2bf_rne(t.y), f2bf_rne(t.z), f2bf_rne(t.w)};
        *(uint2*)&ctxh[gbase + u2 * 4] = *(const uint2*)h4;
    }
}

extern "C" void kernel_launch(void* const* d_in, const int* in_sizes, int n_in,
                              void* d_out, int out_size, void* d_ws, size_t ws_size,
                              hipStream_t stream)
{
    const float* q  = (const float*)d_in[0];
    const float* k  = (const float*)d_in[1];
    const float* v  = (const float*)d_in[2];
    const float* Wq = (const float*)d_in[3];
    const float* bq = (const float*)d_in[4];
    const float* Wk = (const float*)d_in[5];
    const float* bk = (const float*)d_in[6];
    const float* Wv = (const float*)d_in[7];
    const float* bv = (const float*)d_in[8];
    const float* Wo = (const float*)d_in[9];
    const float* bo = (const float*)d_in[10];
    float* out = (float*)d_out;

    // workspace (60 MiB): qp 16 + kp 16 + vt 8 + ctxh 8 + 6 weight planes (12)
    const size_t MB = 1 << 20;
    char* w = (char*)d_ws;
    unsigned* qp = (unsigned*)(w);
    unsigned* kp = (unsigned*)(w + 16 * MB);
    unsigned short* vt   = (unsigned short*)(w + 32 * MB);
    unsigned short* ctxh = (unsigned short*)(w + 40 * MB);
    unsigned short* Wqh = (unsigned short*)(w + 48 * MB);
    unsigned short* Wql = (unsigned short*)(w + 50 * MB);
    unsigned short* Wkh = (unsigned short*)(w + 52 * MB);
    unsigned short* Wkl = (unsigned short*)(w + 54 * MB);
    unsigned short* Wvh = (unsigned short*)(w + 56 * MB);
    unsigned short* Wvl = (unsigned short*)(w + 58 * MB);

    const int NW8 = (D_MODEL * D_MODEL) / 8;      // 131072

    // pre-split the 3 weight matrices (removes 32x-redundant in-loop W conversion)
    conv_w<<<(3 * NW8) / 256, 256, 0, stream>>>(Wq, Wk, Wv, Wqh, Wql, Wkh, Wkl, Wvh, Wvl);

    // fused Q/K/V: grid (32,8,3), x=bm -> id%8 = bm%8 (A-row XCD locality)
    proj_qkv<<<dim3(32, 8, 3), 256, 0, stream>>>(q, k, v,
                                                 Wqh, Wql, Wkh, Wkl, Wvh, Wvl,
                                                 bq, bk, bv, qp, kp, vt);

    // bh on x: all 8 q-blocks of a (b,h) share an XCD (id%8 = bh%8)
    attn_mfma<<<dim3(BATCH * N_HEADS, SEQ / 128), 512, 0, stream>>>(qp, kp, vt, ctxh);

    // O: 64x64 tiles, (64,16) = 1024 blocks = 4/CU (residency ladder)
    proj_o<<<dim3(64, 16), 256, 0, stream>>>(ctxh, Wo, bo, out);
}